// Round 12
// baseline (141.535 us; speedup 1.0000x reference)
//
#include <hip/hip_runtime.h>
#include <math.h>

// Problem constants: B=1, T=2048, D=512, DS=32, EXP=2
#define T_LEN 2048
#define D_DIM 512
#define NCHUNK 64
#define CLEN 32

typedef __bf16 bf16x8 __attribute__((ext_vector_type(8)));
typedef float f32x4 __attribute__((ext_vector_type(4)));

typedef const __attribute__((address_space(1))) void gvoid;
typedef __attribute__((address_space(3))) void lvoid;

// async global->LDS, 16B per lane; lds dest is wave-uniform base + lane*16
__device__ __forceinline__ void async16(const void* g, void* l) {
  __builtin_amdgcn_global_load_lds((gvoid*)g, (lvoid*)l, 16, 0, 0);
}

__device__ __forceinline__ float silu_f(float x) { return x / (1.f + __expf(-x)); }
__device__ __forceinline__ float softplus_f(float x) {
  return fmaxf(x, 0.f) + log1pf(__expf(-fabsf(x)));
}
__device__ __forceinline__ float gelu_f(float x) {
  return 0.5f * x * (1.f + erff(x * 0.70710678118654752440f));
}
__device__ __forceinline__ unsigned short f2bf(float f) {
  union { float f; unsigned u; } v; v.f = f;
  unsigned r = v.u + 0x7FFF + ((v.u >> 16) & 1);  // round-nearest-even
  return (unsigned short)(r >> 16);
}

// ---------------------------------------------------------------------------
// Fused weight prep (8 transpose/convert jobs) + RMSNorm.
// ---------------------------------------------------------------------------
struct TransJobs {
  const float* src[8];
  unsigned short* dst[8];
  int K[8];
  int N[8];
  int tr[8];
  int b0[9];
};

__global__ __launch_bounds__(256) void prep_rms_kernel(
    TransJobs J, const float* __restrict__ x, const float* __restrict__ nw,
    unsigned short* __restrict__ xn) {
  const int b = blockIdx.x;
  if (b >= J.b0[8]) {
    // ---- RMSNorm row t ----
    const int t = b - J.b0[8];
    const float2 v = reinterpret_cast<const float2*>(x + (size_t)t * D_DIM)[threadIdx.x];
    float ss = v.x * v.x + v.y * v.y;
#pragma unroll
    for (int m = 1; m < 64; m <<= 1) ss += __shfl_xor(ss, m);
    __shared__ float wsum[4];
    if ((threadIdx.x & 63) == 0) wsum[threadIdx.x >> 6] = ss;
    __syncthreads();
    const float tot = wsum[0] + wsum[1] + wsum[2] + wsum[3];
    const float scale = rsqrtf(tot * (1.f / D_DIM) + 1e-6f);
    const float2 wv = reinterpret_cast<const float2*>(nw)[threadIdx.x];
    ushort2 o;
    o.x = f2bf(v.x * scale * wv.x);
    o.y = f2bf(v.y * scale * wv.y);
    reinterpret_cast<ushort2*>(xn + (size_t)t * D_DIM)[threadIdx.x] = o;
    return;
  }
  __shared__ float tile[32][33];
  int ji = 0;
#pragma unroll
  for (int i = 1; i < 8; ++i) ji += (b >= J.b0[i]) ? 1 : 0;
  const float* __restrict__ src = J.src[ji];
  unsigned short* __restrict__ dst = J.dst[ji];
  const int K = J.K[ji], N = J.N[ji];
  const int rel = b - J.b0[ji];
  const int nbx = N >> 5;
  const int bx = rel % nbx, by = rel / nbx;
  const int k0 = by * 32, n0 = bx * 32;
  const int i = threadIdx.x & 31;
  const int r = threadIdx.x >> 5;
  if (J.tr[ji]) {
#pragma unroll
    for (int p = 0; p < 4; ++p) {
      const int kk = r + p * 8;
      tile[kk][i] = src[(size_t)(k0 + kk) * N + n0 + i];
    }
    __syncthreads();
#pragma unroll
    for (int p = 0; p < 4; ++p) {
      const int nn = r + p * 8;
      dst[(size_t)(n0 + nn) * K + k0 + i] = f2bf(tile[i][nn]);
    }
  } else {
#pragma unroll
    for (int p = 0; p < 4; ++p) {
      const int kk = r + p * 8;
      dst[(size_t)(k0 + kk) * N + n0 + i] = f2bf(src[(size_t)(k0 + kk) * N + n0 + i]);
    }
  }
}

// ---------------------------------------------------------------------------
// 64x64 MFMA core, BK=64, DOUBLE-BUFFERED async global_load_lds staging.
// LDS linear dest + inverse-swizzled global src + swizzled read (involution).
// ---------------------------------------------------------------------------
__device__ __forceinline__ void gemm64_core(
    const unsigned short* __restrict__ Abf, const unsigned short* __restrict__ Btbf,
    int nt, int lda8, int ldb8, int brow, int bcol,
    bf16x8* __restrict__ As, bf16x8* __restrict__ Bs, f32x4 acc[2][2]) {
  const int tid = threadIdx.x;
  const int lane = tid & 63;
  const int w = tid >> 6;
  const int wrow = (w >> 1) * 32;
  const int wcol = (w & 1) * 32;
  const bf16x8* __restrict__ A8 = reinterpret_cast<const bf16x8*>(Abf);
  const bf16x8* __restrict__ B8 = reinterpret_cast<const bf16x8*>(Btbf);

  const int lr = lane >> 3;
  const int ls = (lane & 7) ^ lr;
  const int wb = w * 64;
  const size_t a0 = (size_t)(brow + w * 8 + lr) * lda8 + ls;
  const size_t a1 = (size_t)(brow + 32 + w * 8 + lr) * lda8 + ls;
  const size_t b0 = (size_t)(bcol + w * 8 + lr) * ldb8 + ls;
  const size_t b1 = (size_t)(bcol + 32 + w * 8 + lr) * ldb8 + ls;

  async16(A8 + a0, As + wb);
  async16(A8 + a1, As + 256 + wb);
  async16(B8 + b0, Bs + wb);
  async16(B8 + b1, Bs + 256 + wb);
  __syncthreads();

  int cur = 0;
  for (int t = 0; t < nt; ++t) {
    if (t + 1 < nt) {
      const int kb = (t + 1) * 8;
      const int nx = (cur ^ 1) * 512;
      async16(A8 + a0 + kb, As + nx + wb);
      async16(A8 + a1 + kb, As + nx + 256 + wb);
      async16(B8 + b0 + kb, Bs + nx + wb);
      async16(B8 + b1 + kb, Bs + nx + 256 + wb);
    }
    const bf16x8* __restrict__ Ac = As + cur * 512;
    const bf16x8* __restrict__ Bc = Bs + cur * 512;
#pragma unroll
    for (int kk = 0; kk < 2; ++kk) {
      const int slot = kk * 4 + (lane >> 4);
      bf16x8 af[2], bf_[2];
#pragma unroll
      for (int m = 0; m < 2; ++m) {
        const int r = wrow + m * 16 + (lane & 15);
        af[m] = Ac[r * 8 + (slot ^ (r & 7))];
      }
#pragma unroll
      for (int n = 0; n < 2; ++n) {
        const int r = wcol + n * 16 + (lane & 15);
        bf_[n] = Bc[r * 8 + (slot ^ (r & 7))];
      }
#pragma unroll
      for (int m = 0; m < 2; ++m)
#pragma unroll
        for (int n = 0; n < 2; ++n)
          acc[m][n] = __builtin_amdgcn_mfma_f32_16x16x32_bf16(af[m], bf_[n], acc[m][n], 0, 0, 0);
    }
    __syncthreads();
    cur ^= 1;
  }
}

// ---------------------------------------------------------------------------
// Fused launch: blocks 0..1023   : [xz | h1] = xn @ [W_in | W_ffn1] (N=2048)
//               blocks 1024..1087: WcombT[:, :512]  = WmT[:, :512] @ W_out^T
//               blocks 1088..1215: WcombT[:, 512:]  = WmT[:, 512:] @ W_ffn2^T
// ---------------------------------------------------------------------------
__global__ __launch_bounds__(256) void gemm_in_combine(
    const unsigned short* __restrict__ xn_bf, const unsigned short* __restrict__ WinF1T,
    float* __restrict__ xz, unsigned short* __restrict__ comb,
    const unsigned short* __restrict__ WmT, const unsigned short* __restrict__ WoutBF,
    const unsigned short* __restrict__ Wf2BF, unsigned short* __restrict__ WcombT) {
  __shared__ bf16x8 As[1024];
  __shared__ bf16x8 Bs[1024];
  f32x4 acc[2][2];
#pragma unroll
  for (int m = 0; m < 2; ++m)
#pragma unroll
    for (int n = 0; n < 2; ++n) acc[m][n] = {0.f, 0.f, 0.f, 0.f};

  const int b = blockIdx.x;
  const int lane = threadIdx.x & 63;
  const int w = threadIdx.x >> 6;
  const int wrow = (w >> 1) * 32;
  const int wcol = (w & 1) * 32;

  if (b < 1024) {
    const int brow = (b >> 5) * 64;
    const int bcol = (b & 31) * 64;
    gemm64_core(xn_bf, WinF1T, 8, 64, 64, brow, bcol, As, Bs, acc);
#pragma unroll
    for (int m = 0; m < 2; ++m) {
#pragma unroll
      for (int n = 0; n < 2; ++n) {
        const int col = bcol + wcol + n * 16 + (lane & 15);
#pragma unroll
        for (int j = 0; j < 4; ++j) {
          const int row = brow + wrow + m * 16 + (lane >> 4) * 4 + j;
          const float v = acc[m][n][j];
          if (col < 1024) {
            xz[(size_t)row * 1024 + col] = v;
          } else {
            comb[(size_t)row * 1536 + 512 + (col - 1024)] = f2bf(gelu_f(v));
          }
        }
      }
    }
  } else if (b < 1088) {
    const int rel = b - 1024;
    const int brow = (rel >> 3) * 64;
    const int bcol = (rel & 7) * 64;
    gemm64_core(WmT, WoutBF, 8, 128, 64, brow, bcol, As, Bs, acc);
#pragma unroll
    for (int m = 0; m < 2; ++m) {
#pragma unroll
      for (int n = 0; n < 2; ++n) {
        const int col = bcol + wcol + n * 16 + (lane & 15);
#pragma unroll
        for (int j = 0; j < 4; ++j) {
          const int row = brow + wrow + m * 16 + (lane >> 4) * 4 + j;
          WcombT[(size_t)row * 1536 + col] = f2bf(acc[m][n][j]);
        }
      }
    }
  } else {
    const int rel = b - 1088;
    const int brow = (rel >> 4) * 64;
    const int bcol = (rel & 15) * 64;
    gemm64_core(WmT + 512, Wf2BF, 8, 128, 64, brow, bcol, As, Bs, acc);
#pragma unroll
    for (int m = 0; m < 2; ++m) {
#pragma unroll
      for (int n = 0; n < 2; ++n) {
        const int col = bcol + wcol + n * 16 + (lane & 15);
#pragma unroll
        for (int j = 0; j < 4; ++j) {
          const int row = brow + wrow + m * 16 + (lane >> 4) * 4 + j;
          WcombT[(size_t)row * 1536 + 512 + col] = f2bf(acc[m][n][j]);
        }
      }
    }
  }
}

// ---------------------------------------------------------------------------
// FUSED conv+siLU+dtbc GEMM: grid (9 col-tiles, 32 row-tiles).
// Phase A: compute xs tile [64 rows][512 ch] by causal conv from xz, write
//          swizzled bf16 into 64KB LDS A-tile (col-group 0 also stores xs f32).
// Phase B: [dt|Bm|Cm](rows, 64 cols) = xs_tile @ WdtBCT-slice, A from LDS,
//          B double-buffered via async16.
// ---------------------------------------------------------------------------
__global__ __launch_bounds__(256) void conv_dtbc_kernel(
    const float* __restrict__ xz, const float* __restrict__ cw,
    const float* __restrict__ cb, const unsigned short* __restrict__ WdtBCT,
    float* __restrict__ xs, float* __restrict__ dt, float* __restrict__ Bm,
    float* __restrict__ Cm, const float* __restrict__ bias) {
  __shared__ bf16x8 XsT[64 * 64];  // 64KB: [row][kslot] swizzled (slot ^ (row&7))
  __shared__ bf16x8 Bs[2 * 512];   // 16KB: B double buffer
  const int tid = threadIdx.x;
  const int lane = tid & 63;
  const int w = tid >> 6;
  const int brow = blockIdx.y * 64;
  const int bcol = blockIdx.x * 64;

  // ---- Phase A: conv + silu into LDS ----
#pragma unroll
  for (int p = 0; p < 16; ++p) {
    const int idx = p * 256 + tid;
    const int row = idx >> 6;
    const int slot = idx & 63;
    const int d0 = slot * 8;
    const int t = brow + row;
    float a[8];
    {
      const float4 c0 = *reinterpret_cast<const float4*>(cb + d0);
      const float4 c1 = *reinterpret_cast<const float4*>(cb + d0 + 4);
      a[0] = c0.x; a[1] = c0.y; a[2] = c0.z; a[3] = c0.w;
      a[4] = c1.x; a[5] = c1.y; a[6] = c1.z; a[7] = c1.w;
    }
    float4 wv[8];
#pragma unroll
    for (int i = 0; i < 8; ++i)
      wv[i] = *reinterpret_cast<const float4*>(cw + (d0 + i) * 4);
#pragma unroll
    for (int k = 0; k < 4; ++k) {
      const int tt = t - 3 + k;
      if (tt >= 0) {
        const float4 x0 = *reinterpret_cast<const float4*>(xz + (size_t)tt * 1024 + d0);
        const float4 x1 = *reinterpret_cast<const float4*>(xz + (size_t)tt * 1024 + d0 + 4);
        const float xv[8] = {x0.x, x0.y, x0.z, x0.w, x1.x, x1.y, x1.z, x1.w};
#pragma unroll
        for (int i = 0; i < 8; ++i) {
          const float wk = (k == 0) ? wv[i].x : (k == 1) ? wv[i].y
                         : (k == 2) ? wv[i].z : wv[i].w;
          a[i] = fmaf(xv[i], wk, a[i]);
        }
      }
    }
#pragma unroll
    for (int i = 0; i < 8; ++i) a[i] = silu_f(a[i]);
    union { bf16x8 v; unsigned u[4]; } pk;
#pragma unroll
    for (int j = 0; j < 4; ++j)
      pk.u[j] = (unsigned)f2bf(a[2 * j]) | ((unsigned)f2bf(a[2 * j + 1]) << 16);
    XsT[row * 64 + (slot ^ (row & 7))] = pk.v;
    if (blockIdx.x == 0) {
      float4* o = reinterpret_cast<float4*>(xs + (size_t)t * 512 + d0);
      o[0] = make_float4(a[0], a[1], a[2], a[3]);
      o[1] = make_float4(a[4], a[5], a[6], a[7]);
    }
  }

  // ---- Phase B: GEMM, A from LDS, B async-staged (double buffer) ----
  const bf16x8* __restrict__ B8 = reinterpret_cast<const bf16x8*>(WdtBCT);
  const int lr = lane >> 3;
  const int ls = (lane & 7) ^ lr;
  const int wb = w * 64;
  const size_t b0 = (size_t)(bcol + w * 8 + lr) * 64 + ls;
  const size_t b1 = (size_t)(bcol + 32 + w * 8 + lr) * 64 + ls;

  async16(B8 + b0, Bs + wb);
  async16(B8 + b1, Bs + 256 + wb);
  __syncthreads();  // covers XsT writes + B tile 0

  const int wrow = (w >> 1) * 32;
  const int wcol = (w & 1) * 32;
  f32x4 acc[2][2];
#pragma unroll
  for (int m = 0; m < 2; ++m)
#pragma unroll
    for (int n = 0; n < 2; ++n) acc[m][n] = {0.f, 0.f, 0.f, 0.f};

  int cur = 0;
  for (int t = 0; t < 8; ++t) {
    if (t + 1 < 8) {
      const int kb = (t + 1) * 8;
      const int nx = (cur ^ 1) * 512;
      async16(B8 + b0 + kb, Bs + nx + wb);
      async16(B8 + b1 + kb, Bs + nx + 256 + wb);
    }
    const bf16x8* __restrict__ Bc = Bs + cur * 512;
#pragma unroll
    for (int kk = 0; kk < 2; ++kk) {
      const int s8 = kk * 4 + (lane >> 4);
      bf16x8 af[2], bf_[2];
#pragma unroll
      for (int m = 0; m < 2; ++m) {
        const int r = wrow + m * 16 + (lane & 15);
        af[m] = XsT[r * 64 + t * 8 + (s8 ^ (r & 7))];
      }
#pragma unroll
      for (int n = 0; n < 2; ++n) {
        const int r = wcol + n * 16 + (lane & 15);
        bf_[n] = Bc[r * 8 + (s8 ^ (r & 7))];
      }
#pragma unroll
      for (int m = 0; m < 2; ++m)
#pragma unroll
        for (int n = 0; n < 2; ++n)
          acc[m][n] = __builtin_amdgcn_mfma_f32_16x16x32_bf16(af[m], bf_[n], acc[m][n], 0, 0, 0);
    }
    __syncthreads();
    cur ^= 1;
  }

#pragma unroll
  for (int m = 0; m < 2; ++m) {
#pragma unroll
    for (int n = 0; n < 2; ++n) {
      const int col = bcol + wcol + n * 16 + (lane & 15);
#pragma unroll
      for (int j = 0; j < 4; ++j) {
        const int row = brow + wrow + m * 16 + (lane >> 4) * 4 + j;
        const float v = acc[m][n][j];
        if (col < 512) {
          dt[(size_t)row * 512 + col] = softplus_f(v + bias[col]);
        } else {
          const int s = col - 512;
          float* p = (s < 32) ? Bm : Cm;
          p[(size_t)row * 32 + (s & 31)] = v;
        }
      }
    }
  }
}

// ---------------------------------------------------------------------------
// Final GEMM: out = x + comb @ Wcomb   (M=2048, N=512, K=1536)
// ---------------------------------------------------------------------------
__global__ __launch_bounds__(256) void gemm64_merge(
    const unsigned short* __restrict__ Abf, const unsigned short* __restrict__ Btbf,
    float* __restrict__ out, const float* __restrict__ resid) {
  __shared__ bf16x8 As[1024];
  __shared__ bf16x8 Bs[1024];
  f32x4 acc[2][2];
#pragma unroll
  for (int m = 0; m < 2; ++m)
#pragma unroll
    for (int n = 0; n < 2; ++n) acc[m][n] = {0.f, 0.f, 0.f, 0.f};
  const int brow = blockIdx.y * 64;
  const int bcol = blockIdx.x * 64;
  gemm64_core(Abf, Btbf, 24, 192, 192, brow, bcol, As, Bs, acc);

  const int lane = threadIdx.x & 63;
  const int w = threadIdx.x >> 6;
  const int wrow = (w >> 1) * 32;
  const int wcol = (w & 1) * 32;
#pragma unroll
  for (int m = 0; m < 2; ++m) {
#pragma unroll
    for (int n = 0; n < 2; ++n) {
      const int col = bcol + wcol + n * 16 + (lane & 15);
#pragma unroll
      for (int j = 0; j < 4; ++j) {
        const int row = brow + wrow + m * 16 + (lane >> 4) * 4 + j;
        out[(size_t)row * 512 + col] = resid[(size_t)row * 512 + col] + acc[m][n][j];
      }
    }
  }
}

// ---------------------------------------------------------------------------
// Fused S1 chunk prep (blocks 0..127) + Gram (blocks 128..191), one launch.
// ---------------------------------------------------------------------------
__global__ __launch_bounds__(256) void prep_gram_kernel(
    const float* __restrict__ dt, const float* __restrict__ xs,
    const float* __restrict__ Bm, const float* __restrict__ Cm,
    const float* __restrict__ log_A,
    unsigned short* __restrict__ U_T, float* __restrict__ E,
    float* __restrict__ V, float* __restrict__ Pc,
    unsigned short* __restrict__ Gm) {
  __shared__ float4 Bls4[CLEN * 8];
  __shared__ float Bls[32][33], Cls[32][33];

  if (blockIdx.x < 128) {
    const int c = blockIdx.x >> 1;
    const int d = (blockIdx.x & 1) * 256 + threadIdx.x;
    Bls4[threadIdx.x] = reinterpret_cast<const float4*>(Bm + c * CLEN * 32)[threadIdx.x];
    __syncthreads();

    const float A = -__expf(log_A[d]);
    float cum = 0.f;
    float e = 1.f;
    float vacc[32];
#pragma unroll
    for (int s = 0; s < 32; ++s) vacc[s] = 0.f;
    unsigned pk[16];
#pragma unroll
    for (int t = 0; t < CLEN; ++t) {
      const int tg = c * CLEN + t;
      const float dtv = dt[(size_t)tg * D_DIM + d];
      const float xv  = xs[(size_t)tg * D_DIM + d];
      const float la = fminf(fmaxf(dtv * A, -20.f), 20.f);
      cum += la;
      e = __expf(cum);
      E[(size_t)tg * D_DIM + d] = e;
      const float u = __expf(-cum) * dtv * xv;
      const unsigned short ub = f2bf(u);
      if ((t & 1) == 0) pk[t >> 1] = (unsigned)ub;
      else              pk[t >> 1] |= ((unsigned)ub) << 16;
#pragma unroll
      for (int s4 = 0; s4 < 8; ++s4) {
        const float4 b = Bls4[t * 8 + s4];
        vacc[s4 * 4 + 0] = fmaf(u, b.x, vacc[s4 * 4 + 0]);
        vacc[s4 * 4 + 1] = fmaf(u, b.y, vacc[s4 * 4 + 1]);
        vacc[s4 * 4 + 2] = fmaf(u, b.z, vacc[s4 * 4 + 2]);
        vacc[s4 * 4 + 3] = fmaf(u, b.w, vacc[s4 * 4 + 3]);
      }
    }
    {
      uint4* dst = reinterpret_cast<uint4*>(U_T + (size_t)d * T_LEN + c * CLEN);
      dst[0] = make_uint4(pk[0], pk[1], pk[2], pk[3]);
      dst[1] = make_uint4(pk[4], pk[5], pk[6], pk[7]);
      dst[2] = make_uint4(pk[8], pk[9], pk[10], pk[11]);
      dst[3] = make_uint4(pk[12], pk[13], pk[14], pk[15]);
    }
    {
      float4* dst = reinterpret_cast<float4*>(V + ((size_t)c * D_DIM + d) * 32);
#pragma unroll
      for (int s4 = 0; s4 < 8; ++s4)
        dst[s4] = make_float4(vacc[s4 * 4], vacc[s4 * 4 + 1], vacc[s4 * 4 + 2], vacc[s4 * 4 + 3]);
    }
    Pc[c * D_DIM + d] = e;
  } else {
    const int c = blockIdx.x - 128;
    {
      const int t = threadIdx.x >> 3;
      const int s4 = threadIdx.x & 7;
      const float4 b = reinterpret_cast<const float4*>(Bm + (c * CLEN + t) * 32)[s4];
      const float4 cc = reinterpret_cast<const float4*>(Cm + (c * CLEN + t) * 32)[s4];
      Bls[t][s4 * 4 + 0] = b.x;  Bls[t][s4 * 4 + 1] = b.y;
      Bls[t][s4 * 4 + 2] = b.z;  Bls[t][s4 * 4 + 3] = b.w;
      Cls[t][s4 * 4 + 0] = cc.x; Cls[t][s4 * 4 + 1] = cc.y;
      Cls[t][s4 * 4 + 2] = cc.z; Cls[t][s4 * 4 + 3] = cc.w;
    }
    __syncthreads();
    const int t = threadIdx.x >> 3;
    const int tp0 = (threadIdx.x & 7) * 4;
    float g[4];
#pragma unroll
    for (int q = 0; q < 4; ++q) {
      const int tp = tp0 + q;
      float acc = 0.f;
      if (tp <= t) {
#pragma unroll
        for (int s = 0; s < 32; ++s) acc = fmaf(Cls[t][s], Bls[tp][s], acc);
      }
      g[q] = acc;
    }
    ushort4 o;
    o.x = f2bf(g[0]); o.y = f2bf(g[1]); o.z = f2bf(g[2]); o.w = f2bf(g[3]);
    reinterpret_cast<ushort4*>(Gm + c * 1024)[threadIdx.x] = o;
  }
}

// ---------------------------------------------------------------------------
// S2 state scan
// ---------------------------------------------------------------------------
__global__ __launch_bounds__(256) void state_scan_kernel(
    const float* __restrict__ V, const float* __restrict__ Pc,
    float* __restrict__ Hin) {
  const int gt = blockIdx.x * 256 + threadIdx.x;  // d*32+s
  const int d = gt >> 5;
  float h = 0.f;
  for (int c = 0; c < NCHUNK; ++c) {
    Hin[c * 16384 + gt] = h;
    h = Pc[c * D_DIM + d] * (h + V[c * 16384 + gt]);
  }
}

// ---------------------------------------------------------------------------
// S3: intra+inter output + fused gate -> comb[:, :512] (bf16, ld 1536)
// ---------------------------------------------------------------------------
__global__ __launch_bounds__(256) void ssm_out_kernel(
    const unsigned short* __restrict__ Gm, const unsigned short* __restrict__ U_T,
    const float* __restrict__ Hin, const float* __restrict__ Cm,
    const float* __restrict__ E, const float* __restrict__ xs,
    const float* __restrict__ Dp, const float* __restrict__ xz,
    unsigned short* __restrict__ comb) {
  const int c = blockIdx.x;
  const int dt0 = blockIdx.y * 64;
  __shared__ bf16x8 Als[32 * 8];
  __shared__ bf16x8 Bls[64 * 8];
  const int tid = threadIdx.x;

  if (tid < 128) {
    const int t = tid >> 2, q = tid & 3;
    Als[t * 8 + (q ^ (t & 7))] =
        *reinterpret_cast<const bf16x8*>(Gm + c * 1024 + t * 32 + q * 8);
  } else {
    const int i = tid - 128;
    const int t = i >> 2, q = i & 3;
    const float* cp = Cm + (c * CLEN + t) * 32 + q * 8;
    const float4 c0 = *reinterpret_cast<const float4*>(cp);
    const float4 c1 = *reinterpret_cast<const float4*>(cp + 4);
    union { bf16x8 v; unsigned short u[8]; } wv;
    wv.u[0] = f2bf(c0.x); wv.u[1] = f2bf(c0.y); wv.u[2] = f2bf(c0.z); wv.u[3] = f2bf(c0.w);
    wv.u[4] = f2bf(c1.x); wv.u[5] = f2bf(c1.y); wv.u[6] = f2bf(c1.z); wv.u[7] = f2bf(c1.w);
    Als[t * 8 + ((4 + q) ^ (t & 7))] = wv.v;
  }
  {
    const int dd = tid >> 2, q = tid & 3;
    Bls[dd * 8 + (q ^ (dd & 7))] = *reinterpret_cast<const bf16x8*>(
        U_T + (size_t)(dt0 + dd) * T_LEN + c * CLEN + q * 8);
    const float* hp = Hin + ((size_t)c * D_DIM + dt0 + dd) * 32 + q * 8;
    const float4 h0 = *reinterpret_cast<const float4*>(hp);
    const float4 h1 = *reinterpret_cast<const float4*>(hp + 4);
    union { bf16x8 v; unsigned short u[8]; } wv;
    wv.u[0] = f2bf(h0.x); wv.u[1] = f2bf(h0.y); wv.u[2] = f2bf(h0.z); wv.u[3] = f2bf(h0.w);
    wv.u[4] = f2bf(h1.x); wv.u[5] = f2bf(h1.y); wv.u[6] = f2bf(h1.z); wv.u[7] = f2bf(h1.w);
    Bls[dd * 8 + ((4 + q) ^ (dd & 7))] = wv.v;
  }
  __syncthreads();

  const int lane = tid & 63;
  const int w = tid >> 6;
  const int wcol = w * 16;
  f32x4 acc[2];
  acc[0] = {0.f, 0.f, 0.f, 0.f};
  acc[1] = {0.f, 0.f, 0.f, 0.f};
#pragma unroll
  for (int kk = 0; kk < 2; ++kk) {
    const int slot = kk * 4 + (lane >> 4);
    const int rb = wcol + (lane & 15);
    const bf16x8 bfrag = Bls[rb * 8 + (slot ^ (rb & 7))];
#pragma unroll
    for (int m = 0; m < 2; ++m) {
      const int r = m * 16 + (lane & 15);
      const bf16x8 afrag = Als[r * 8 + (slot ^ (r & 7))];
      acc[m] = __builtin_amdgcn_mfma_f32_16x16x32_bf16(afrag, bfrag, acc[m], 0, 0, 0);
    }
  }
  const int dg = dt0 + wcol + (lane & 15);
  const float dpv = Dp[dg];
#pragma unroll
  for (int m = 0; m < 2; ++m) {
#pragma unroll
    for (int j = 0; j < 4; ++j) {
      const int tg = c * CLEN + m * 16 + (lane >> 4) * 4 + j;
      const float y = E[(size_t)tg * D_DIM + dg] * acc[m][j];
      const float xv = xs[(size_t)tg * D_DIM + dg];
      const float zv = xz[(size_t)tg * 1024 + 512 + dg];
      comb[(size_t)tg * 1536 + dg] = f2bf(fmaf(xv, dpv, y) * silu_f(zv));
    }
  }
}

// ---------------------------------------------------------------------------
extern "C" void kernel_launch(void* const* d_in, const int* in_sizes, int n_in,
                              void* d_out, int out_size, void* d_ws, size_t ws_size,
                              hipStream_t stream) {
  const float* x      = (const float*)d_in[0];
  const float* norm_w = (const float*)d_in[1];
  const float* W_in   = (const float*)d_in[2];
  const float* conv_w = (const float*)d_in[3];
  const float* conv_b = (const float*)d_in[4];
  const float* W_dt   = (const float*)d_in[5];
  const float* b_dt   = (const float*)d_in[6];
  const float* W_B    = (const float*)d_in[7];
  const float* W_C    = (const float*)d_in[8];
  const float* W_out  = (const float*)d_in[9];
  const float* log_A  = (const float*)d_in[10];
  const float* D_par  = (const float*)d_in[11];
  const float* W_ffn1 = (const float*)d_in[12];
  const float* W_ffn2 = (const float*)d_in[13];
  const float* W_mrg  = (const float*)d_in[14];
  float* out = (float*)d_out;

  const size_t M1 = 1u << 20;
  char* ws = (char*)d_ws;
  size_t off = 0;
  auto alloc_f = [&](size_t n) { float* p = (float*)(ws + off); off += n * 4; return p; };
  auto alloc_h = [&](size_t n) { unsigned short* p = (unsigned short*)(ws + off); off += n * 2; return p; };

  float* xz  = alloc_f(2 * M1);   // [2048][1024]
  float* xs  = alloc_f(M1);
  float* dt  = alloc_f(M1);
  float* E   = alloc_f(M1);
  float* V   = alloc_f(M1);       // [64][512][32]
  float* Hin = alloc_f(M1);       // [64][512][32]
  float* Bm  = alloc_f(1 << 16);
  float* Cm  = alloc_f(1 << 16);
  float* Pc  = alloc_f(NCHUNK * D_DIM);
  unsigned short* U_T    = alloc_h(M1);            // [512][2048]
  unsigned short* Gm     = alloc_h(NCHUNK * 1024);
  unsigned short* xn_bf  = alloc_h(M1);
  unsigned short* comb   = alloc_h(2048 * 1536);   // [g | h1]
  unsigned short* WinF1T = alloc_h(2048 * 512);    // W_in cols ++ W_ffn1 cols
  unsigned short* WdtBCT = alloc_h(576 * 512);     // W_dt ++ W_B ++ W_C
  unsigned short* WmT    = alloc_h(512 * 1024);    // W_mrg^T
  unsigned short* WoutBF = alloc_h(512 * 512);     // W_out row-major bf16
  unsigned short* Wf2BF  = alloc_h(1024 * 512);    // W_ffn2 row-major bf16
  unsigned short* WcombT = alloc_h(512 * 1536);    // combined merge weights^T

  // --- fused weight prep + rmsnorm (1 launch) ---
  TransJobs J;
  J.src[0] = W_in;   J.dst[0] = WinF1T;              J.K[0] = 512;  J.N[0] = 1024; J.tr[0] = 1;
  J.src[1] = W_ffn1; J.dst[1] = WinF1T + 1024 * 512; J.K[1] = 512;  J.N[1] = 1024; J.tr[1] = 1;
  J.src[2] = W_dt;   J.dst[2] = WdtBCT;              J.K[2] = 512;  J.N[2] = 512;  J.tr[2] = 1;
  J.src[3] = W_B;    J.dst[3] = WdtBCT + 512 * 512;  J.K[3] = 512;  J.N[3] = 32;   J.tr[3] = 1;
  J.src[4] = W_C;    J.dst[4] = WdtBCT + 544 * 512;  J.K[4] = 512;  J.N[4] = 32;   J.tr[4] = 1;
  J.src[5] = W_mrg;  J.dst[5] = WmT;                 J.K[5] = 1024; J.N[5] = 512;  J.tr[5] = 1;
  J.src[6] = W_out;  J.dst[6] = WoutBF;              J.K[6] = 512;  J.N[6] = 512;  J.tr[6] = 0;
  J.src[7] = W_ffn2; J.dst[7] = Wf2BF;               J.K[7] = 1024; J.N[7] = 512;  J.tr[7] = 0;
  int bacc = 0;
  for (int i = 0; i < 8; ++i) {
    J.b0[i] = bacc;
    bacc += (J.N[i] >> 5) * (J.K[i] >> 5);
  }
  J.b0[8] = bacc;  // 2592
  prep_rms_kernel<<<bacc + T_LEN, 256, 0, stream>>>(J, x, norm_w, xn_bf);

  // 2. fused: input projection (1024 blks) + weight combine (192 blks)
  gemm_in_combine<<<1216, 256, 0, stream>>>(
      xn_bf, WinF1T, xz, comb, WmT, WoutBF, Wf2BF, WcombT);
  // 3. FUSED conv + silu + [dt|Bm|Cm] GEMM
  conv_dtbc_kernel<<<dim3(9, 32), 256, 0, stream>>>(
      xz, conv_w, conv_b, WdtBCT, xs, dt, Bm, Cm, b_dt);
  // 4. fused chunk prep + gram
  prep_gram_kernel<<<192, 256, 0, stream>>>(dt, xs, Bm, Cm, log_A, U_T, E, V, Pc, Gm);
  // 5. inter-chunk state scan
  state_scan_kernel<<<64, 256, 0, stream>>>(V, Pc, Hin);
  // 6. SSM output + fused gate -> comb[:, :512]
  ssm_out_kernel<<<dim3(NCHUNK, 8), 256, 0, stream>>>(Gm, U_T, Hin, Cm, E, xs, D_par, xz, comb);
  // 7. out = x + comb @ Wcomb  (K=1536, residual fused)
  gemm64_merge<<<dim3(8, 32), 256, 0, stream>>>(comb, WcombT, out, x);
}

// Round 13
// 86.870 us; speedup vs baseline: 1.6293x; 1.6293x over previous
//
#include <hip/hip_runtime.h>
#include <math.h>

// Problem constants: B=1, T=2048, D=512, DS=32, EXP=2
#define T_LEN 2048
#define D_DIM 512
#define NCHUNK 64
#define CLEN 32

typedef __bf16 bf16x8 __attribute__((ext_vector_type(8)));
typedef float f32x4 __attribute__((ext_vector_type(4)));

typedef const __attribute__((address_space(1))) void gvoid;
typedef __attribute__((address_space(3))) void lvoid;

// async global->LDS, 16B per lane; lds dest is wave-uniform base + lane*16
__device__ __forceinline__ void async16(const void* g, void* l) {
  __builtin_amdgcn_global_load_lds((gvoid*)g, (lvoid*)l, 16, 0, 0);
}

__device__ __forceinline__ float silu_f(float x) { return x / (1.f + __expf(-x)); }
__device__ __forceinline__ float softplus_f(float x) {
  return fmaxf(x, 0.f) + log1pf(__expf(-fabsf(x)));
}
__device__ __forceinline__ float gelu_f(float x) {
  return 0.5f * x * (1.f + erff(x * 0.70710678118654752440f));
}
__device__ __forceinline__ unsigned short f2bf(float f) {
  union { float f; unsigned u; } v; v.f = f;
  unsigned r = v.u + 0x7FFF + ((v.u >> 16) & 1);  // round-nearest-even
  return (unsigned short)(r >> 16);
}

// ---------------------------------------------------------------------------
// Fused weight prep (8 transpose/convert jobs) + RMSNorm.
// ---------------------------------------------------------------------------
struct TransJobs {
  const float* src[8];
  unsigned short* dst[8];
  int K[8];
  int N[8];
  int tr[8];
  int b0[9];
};

__global__ __launch_bounds__(256) void prep_rms_kernel(
    TransJobs J, const float* __restrict__ x, const float* __restrict__ nw,
    unsigned short* __restrict__ xn) {
  const int b = blockIdx.x;
  if (b >= J.b0[8]) {
    // ---- RMSNorm row t ----
    const int t = b - J.b0[8];
    const float2 v = reinterpret_cast<const float2*>(x + (size_t)t * D_DIM)[threadIdx.x];
    float ss = v.x * v.x + v.y * v.y;
#pragma unroll
    for (int m = 1; m < 64; m <<= 1) ss += __shfl_xor(ss, m);
    __shared__ float wsum[4];
    if ((threadIdx.x & 63) == 0) wsum[threadIdx.x >> 6] = ss;
    __syncthreads();
    const float tot = wsum[0] + wsum[1] + wsum[2] + wsum[3];
    const float scale = rsqrtf(tot * (1.f / D_DIM) + 1e-6f);
    const float2 wv = reinterpret_cast<const float2*>(nw)[threadIdx.x];
    ushort2 o;
    o.x = f2bf(v.x * scale * wv.x);
    o.y = f2bf(v.y * scale * wv.y);
    reinterpret_cast<ushort2*>(xn + (size_t)t * D_DIM)[threadIdx.x] = o;
    return;
  }
  __shared__ float tile[32][33];
  int ji = 0;
#pragma unroll
  for (int i = 1; i < 8; ++i) ji += (b >= J.b0[i]) ? 1 : 0;
  const float* __restrict__ src = J.src[ji];
  unsigned short* __restrict__ dst = J.dst[ji];
  const int K = J.K[ji], N = J.N[ji];
  const int rel = b - J.b0[ji];
  const int nbx = N >> 5;
  const int bx = rel % nbx, by = rel / nbx;
  const int k0 = by * 32, n0 = bx * 32;
  const int i = threadIdx.x & 31;
  const int r = threadIdx.x >> 5;
  if (J.tr[ji]) {
#pragma unroll
    for (int p = 0; p < 4; ++p) {
      const int kk = r + p * 8;
      tile[kk][i] = src[(size_t)(k0 + kk) * N + n0 + i];
    }
    __syncthreads();
#pragma unroll
    for (int p = 0; p < 4; ++p) {
      const int nn = r + p * 8;
      dst[(size_t)(n0 + nn) * K + k0 + i] = f2bf(tile[i][nn]);
    }
  } else {
#pragma unroll
    for (int p = 0; p < 4; ++p) {
      const int kk = r + p * 8;
      dst[(size_t)(k0 + kk) * N + n0 + i] = f2bf(src[(size_t)(k0 + kk) * N + n0 + i]);
    }
  }
}

// ---------------------------------------------------------------------------
// 64x64 MFMA core (parameterized tid), BK=64, double-buffered async staging.
// LDS linear dest + inverse-swizzled global src + swizzled read (involution).
// ---------------------------------------------------------------------------
__device__ __forceinline__ void gemm64_core_t(
    int tid,
    const unsigned short* __restrict__ Abf, const unsigned short* __restrict__ Btbf,
    int nt, int lda8, int ldb8, int brow, int bcol,
    bf16x8* __restrict__ As, bf16x8* __restrict__ Bs, f32x4 acc[2][2]) {
  const int lane = tid & 63;
  const int w = tid >> 6;
  const int wrow = (w >> 1) * 32;
  const int wcol = (w & 1) * 32;
  const bf16x8* __restrict__ A8 = reinterpret_cast<const bf16x8*>(Abf);
  const bf16x8* __restrict__ B8 = reinterpret_cast<const bf16x8*>(Btbf);

  const int lr = lane >> 3;
  const int ls = (lane & 7) ^ lr;
  const int wb = w * 64;
  const size_t a0 = (size_t)(brow + w * 8 + lr) * lda8 + ls;
  const size_t a1 = (size_t)(brow + 32 + w * 8 + lr) * lda8 + ls;
  const size_t b0 = (size_t)(bcol + w * 8 + lr) * ldb8 + ls;
  const size_t b1 = (size_t)(bcol + 32 + w * 8 + lr) * ldb8 + ls;

  async16(A8 + a0, As + wb);
  async16(A8 + a1, As + 256 + wb);
  async16(B8 + b0, Bs + wb);
  async16(B8 + b1, Bs + 256 + wb);
  __syncthreads();

  int cur = 0;
  for (int t = 0; t < nt; ++t) {
    if (t + 1 < nt) {
      const int kb = (t + 1) * 8;
      const int nx = (cur ^ 1) * 512;
      async16(A8 + a0 + kb, As + nx + wb);
      async16(A8 + a1 + kb, As + nx + 256 + wb);
      async16(B8 + b0 + kb, Bs + nx + wb);
      async16(B8 + b1 + kb, Bs + nx + 256 + wb);
    }
    const bf16x8* __restrict__ Ac = As + cur * 512;
    const bf16x8* __restrict__ Bc = Bs + cur * 512;
#pragma unroll
    for (int kk = 0; kk < 2; ++kk) {
      const int slot = kk * 4 + (lane >> 4);
      bf16x8 af[2], bf_[2];
#pragma unroll
      for (int m = 0; m < 2; ++m) {
        const int r = wrow + m * 16 + (lane & 15);
        af[m] = Ac[r * 8 + (slot ^ (r & 7))];
      }
#pragma unroll
      for (int n = 0; n < 2; ++n) {
        const int r = wcol + n * 16 + (lane & 15);
        bf_[n] = Bc[r * 8 + (slot ^ (r & 7))];
      }
#pragma unroll
      for (int m = 0; m < 2; ++m)
#pragma unroll
        for (int n = 0; n < 2; ++n)
          acc[m][n] = __builtin_amdgcn_mfma_f32_16x16x32_bf16(af[m], bf_[n], acc[m][n], 0, 0, 0);
    }
    __syncthreads();
    cur ^= 1;
  }
}

__device__ __forceinline__ void gemm64_core(
    const unsigned short* __restrict__ Abf, const unsigned short* __restrict__ Btbf,
    int nt, int lda8, int ldb8, int brow, int bcol,
    bf16x8* __restrict__ As, bf16x8* __restrict__ Bs, f32x4 acc[2][2]) {
  gemm64_core_t(threadIdx.x, Abf, Btbf, nt, lda8, ldb8, brow, bcol, As, Bs, acc);
}

// ---------------------------------------------------------------------------
// Fused launch: blocks 0..1023   : [xz | h1] = xn @ [W_in | W_ffn1] (N=2048)
//               blocks 1024..1087: WcombT[:, :512]  = WmT[:, :512] @ W_out^T
//               blocks 1088..1215: WcombT[:, 512:]  = WmT[:, 512:] @ W_ffn2^T
// ---------------------------------------------------------------------------
__global__ __launch_bounds__(256) void gemm_in_combine(
    const unsigned short* __restrict__ xn_bf, const unsigned short* __restrict__ WinF1T,
    float* __restrict__ xz, unsigned short* __restrict__ comb,
    const unsigned short* __restrict__ WmT, const unsigned short* __restrict__ WoutBF,
    const unsigned short* __restrict__ Wf2BF, unsigned short* __restrict__ WcombT) {
  __shared__ bf16x8 As[1024];
  __shared__ bf16x8 Bs[1024];
  f32x4 acc[2][2];
#pragma unroll
  for (int m = 0; m < 2; ++m)
#pragma unroll
    for (int n = 0; n < 2; ++n) acc[m][n] = {0.f, 0.f, 0.f, 0.f};

  const int b = blockIdx.x;
  const int lane = threadIdx.x & 63;
  const int w = threadIdx.x >> 6;
  const int wrow = (w >> 1) * 32;
  const int wcol = (w & 1) * 32;

  if (b < 1024) {
    const int brow = (b >> 5) * 64;
    const int bcol = (b & 31) * 64;
    gemm64_core(xn_bf, WinF1T, 8, 64, 64, brow, bcol, As, Bs, acc);
#pragma unroll
    for (int m = 0; m < 2; ++m) {
#pragma unroll
      for (int n = 0; n < 2; ++n) {
        const int col = bcol + wcol + n * 16 + (lane & 15);
#pragma unroll
        for (int j = 0; j < 4; ++j) {
          const int row = brow + wrow + m * 16 + (lane >> 4) * 4 + j;
          const float v = acc[m][n][j];
          if (col < 1024) {
            xz[(size_t)row * 1024 + col] = v;
          } else {
            comb[(size_t)row * 1536 + 512 + (col - 1024)] = f2bf(gelu_f(v));
          }
        }
      }
    }
  } else if (b < 1088) {
    const int rel = b - 1024;
    const int brow = (rel >> 3) * 64;
    const int bcol = (rel & 7) * 64;
    gemm64_core(WmT, WoutBF, 8, 128, 64, brow, bcol, As, Bs, acc);
#pragma unroll
    for (int m = 0; m < 2; ++m) {
#pragma unroll
      for (int n = 0; n < 2; ++n) {
        const int col = bcol + wcol + n * 16 + (lane & 15);
#pragma unroll
        for (int j = 0; j < 4; ++j) {
          const int row = brow + wrow + m * 16 + (lane >> 4) * 4 + j;
          WcombT[(size_t)row * 1536 + col] = f2bf(acc[m][n][j]);
        }
      }
    }
  } else {
    const int rel = b - 1088;
    const int brow = (rel >> 4) * 64;
    const int bcol = (rel & 15) * 64;
    gemm64_core(WmT + 512, Wf2BF, 8, 128, 64, brow, bcol, As, Bs, acc);
#pragma unroll
    for (int m = 0; m < 2; ++m) {
#pragma unroll
      for (int n = 0; n < 2; ++n) {
        const int col = bcol + wcol + n * 16 + (lane & 15);
#pragma unroll
        for (int j = 0; j < 4; ++j) {
          const int row = brow + wrow + m * 16 + (lane >> 4) * 4 + j;
          WcombT[(size_t)row * 1536 + 512 + col] = f2bf(acc[m][n][j]);
        }
      }
    }
  }
}

// ---------------------------------------------------------------------------
// GEMM (64-core): [dt | Bm | Cm] = xs @ [W_dt|W_B|W_C]  (N=576)
// ---------------------------------------------------------------------------
__global__ __launch_bounds__(256) void gemm64_dtbc(
    const unsigned short* __restrict__ Abf, const unsigned short* __restrict__ Btbf,
    float* __restrict__ dt, float* __restrict__ Bm, float* __restrict__ Cm,
    const float* __restrict__ bias) {
  __shared__ bf16x8 As[1024];
  __shared__ bf16x8 Bs[1024];
  f32x4 acc[2][2];
#pragma unroll
  for (int m = 0; m < 2; ++m)
#pragma unroll
    for (int n = 0; n < 2; ++n) acc[m][n] = {0.f, 0.f, 0.f, 0.f};
  const int brow = blockIdx.y * 64;
  const int bcol = blockIdx.x * 64;
  gemm64_core(Abf, Btbf, 8, 64, 64, brow, bcol, As, Bs, acc);

  const int lane = threadIdx.x & 63;
  const int w = threadIdx.x >> 6;
  const int wrow = (w >> 1) * 32;
  const int wcol = (w & 1) * 32;
#pragma unroll
  for (int m = 0; m < 2; ++m) {
#pragma unroll
    for (int n = 0; n < 2; ++n) {
      const int col = bcol + wcol + n * 16 + (lane & 15);
#pragma unroll
      for (int j = 0; j < 4; ++j) {
        const int row = brow + wrow + m * 16 + (lane >> 4) * 4 + j;
        const float v = acc[m][n][j];
        if (col < 512) {
          dt[(size_t)row * 512 + col] = softplus_f(v + bias[col]);
        } else {
          const int s = col - 512;
          float* p = (s < 32) ? Bm : Cm;
          p[(size_t)row * 32 + (s & 31)] = v;
        }
      }
    }
  }
}

// ---------------------------------------------------------------------------
// Final GEMM, split-K WITHIN block: 512 threads = 2 groups x 4 waves.
// Group g computes K range [g*768, (g+1)*768) (nt=12) into private LDS bufs;
// group 1's partial is reduced via LDS; group 0 writes out = resid + sum.
// Grid stays (8,32) = 256 blocks; 64KB LDS; serial K-depth halves.
// ---------------------------------------------------------------------------
__global__ __launch_bounds__(512) void gemm64_merge_kp(
    const unsigned short* __restrict__ Abf, const unsigned short* __restrict__ Btbf,
    float* __restrict__ out, const float* __restrict__ resid) {
  __shared__ bf16x8 As[2][1024];
  __shared__ bf16x8 Bs[2][1024];
  const int tid = threadIdx.x;
  const int g = tid >> 8;       // K-group
  const int t256 = tid & 255;
  f32x4 acc[2][2];
#pragma unroll
  for (int m = 0; m < 2; ++m)
#pragma unroll
    for (int n = 0; n < 2; ++n) acc[m][n] = {0.f, 0.f, 0.f, 0.f};
  const int brow = blockIdx.y * 64;
  const int bcol = blockIdx.x * 64;
  // K offset: g*768 bf16 = g*96 bf16x8 units
  gemm64_core_t(t256, Abf + (size_t)g * 768, Btbf + (size_t)g * 768,
                12, 192, 192, brow, bcol, As[g], Bs[g], acc);

  const int lane = t256 & 63;
  const int w = t256 >> 6;
  const int wrow = (w >> 1) * 32;
  const int wcol = (w & 1) * 32;
  float* red = reinterpret_cast<float*>(&As[0][0]);  // 64x64 f32 = 16KB
  __syncthreads();
  if (g == 1) {
#pragma unroll
    for (int m = 0; m < 2; ++m)
#pragma unroll
      for (int n = 0; n < 2; ++n)
#pragma unroll
        for (int j = 0; j < 4; ++j) {
          const int r = wrow + m * 16 + (lane >> 4) * 4 + j;
          const int c = wcol + n * 16 + (lane & 15);
          red[r * 64 + c] = acc[m][n][j];
        }
  }
  __syncthreads();
  if (g == 0) {
#pragma unroll
    for (int m = 0; m < 2; ++m) {
#pragma unroll
      for (int n = 0; n < 2; ++n) {
        const int c = wcol + n * 16 + (lane & 15);
        const int col = bcol + c;
#pragma unroll
        for (int j = 0; j < 4; ++j) {
          const int r = wrow + m * 16 + (lane >> 4) * 4 + j;
          const int row = brow + r;
          out[(size_t)row * 512 + col] =
              resid[(size_t)row * 512 + col] + acc[m][n][j] + red[r * 64 + c];
        }
      }
    }
  }
}

// ---------------------------------------------------------------------------
// Causal depthwise conv (k=4) + bias + SiLU -> f32 + bf16
// ---------------------------------------------------------------------------
__global__ __launch_bounds__(256) void conv_silu_kernel(
    const float* __restrict__ xz, const float* __restrict__ cw,
    const float* __restrict__ cb, float* __restrict__ xs,
    unsigned short* __restrict__ xs_bf) {
  const int idx = blockIdx.x * 256 + threadIdx.x;
  const int t = idx >> 9;
  const int d = idx & 511;
  const float4 w = reinterpret_cast<const float4*>(cw)[d];
  float acc = cb[d];
  const float wk[4] = {w.x, w.y, w.z, w.w};
#pragma unroll
  for (int k = 0; k < 4; ++k) {
    const int tt = t - 3 + k;
    if (tt >= 0) acc = fmaf(xz[(size_t)tt * 1024 + d], wk[k], acc);
  }
  const float s = silu_f(acc);
  xs[idx] = s;
  xs_bf[idx] = f2bf(s);
}

// ---------------------------------------------------------------------------
// Fused S1 chunk prep (blocks 0..127) + Gram (blocks 128..191), one launch.
// ---------------------------------------------------------------------------
__global__ __launch_bounds__(256) void prep_gram_kernel(
    const float* __restrict__ dt, const float* __restrict__ xs,
    const float* __restrict__ Bm, const float* __restrict__ Cm,
    const float* __restrict__ log_A,
    unsigned short* __restrict__ U_T, float* __restrict__ E,
    float* __restrict__ V, float* __restrict__ Pc,
    unsigned short* __restrict__ Gm) {
  __shared__ float4 Bls4[CLEN * 8];
  __shared__ float Bls[32][33], Cls[32][33];

  if (blockIdx.x < 128) {
    const int c = blockIdx.x >> 1;
    const int d = (blockIdx.x & 1) * 256 + threadIdx.x;
    Bls4[threadIdx.x] = reinterpret_cast<const float4*>(Bm + c * CLEN * 32)[threadIdx.x];
    __syncthreads();

    const float A = -__expf(log_A[d]);
    float cum = 0.f;
    float e = 1.f;
    float vacc[32];
#pragma unroll
    for (int s = 0; s < 32; ++s) vacc[s] = 0.f;
    unsigned pk[16];
#pragma unroll
    for (int t = 0; t < CLEN; ++t) {
      const int tg = c * CLEN + t;
      const float dtv = dt[(size_t)tg * D_DIM + d];
      const float xv  = xs[(size_t)tg * D_DIM + d];
      const float la = fminf(fmaxf(dtv * A, -20.f), 20.f);
      cum += la;
      e = __expf(cum);
      E[(size_t)tg * D_DIM + d] = e;
      const float u = __expf(-cum) * dtv * xv;
      const unsigned short ub = f2bf(u);
      if ((t & 1) == 0) pk[t >> 1] = (unsigned)ub;
      else              pk[t >> 1] |= ((unsigned)ub) << 16;
#pragma unroll
      for (int s4 = 0; s4 < 8; ++s4) {
        const float4 b = Bls4[t * 8 + s4];
        vacc[s4 * 4 + 0] = fmaf(u, b.x, vacc[s4 * 4 + 0]);
        vacc[s4 * 4 + 1] = fmaf(u, b.y, vacc[s4 * 4 + 1]);
        vacc[s4 * 4 + 2] = fmaf(u, b.z, vacc[s4 * 4 + 2]);
        vacc[s4 * 4 + 3] = fmaf(u, b.w, vacc[s4 * 4 + 3]);
      }
    }
    {
      uint4* dst = reinterpret_cast<uint4*>(U_T + (size_t)d * T_LEN + c * CLEN);
      dst[0] = make_uint4(pk[0], pk[1], pk[2], pk[3]);
      dst[1] = make_uint4(pk[4], pk[5], pk[6], pk[7]);
      dst[2] = make_uint4(pk[8], pk[9], pk[10], pk[11]);
      dst[3] = make_uint4(pk[12], pk[13], pk[14], pk[15]);
    }
    {
      float4* dst = reinterpret_cast<float4*>(V + ((size_t)c * D_DIM + d) * 32);
#pragma unroll
      for (int s4 = 0; s4 < 8; ++s4)
        dst[s4] = make_float4(vacc[s4 * 4], vacc[s4 * 4 + 1], vacc[s4 * 4 + 2], vacc[s4 * 4 + 3]);
    }
    Pc[c * D_DIM + d] = e;
  } else {
    const int c = blockIdx.x - 128;
    {
      const int t = threadIdx.x >> 3;
      const int s4 = threadIdx.x & 7;
      const float4 b = reinterpret_cast<const float4*>(Bm + (c * CLEN + t) * 32)[s4];
      const float4 cc = reinterpret_cast<const float4*>(Cm + (c * CLEN + t) * 32)[s4];
      Bls[t][s4 * 4 + 0] = b.x;  Bls[t][s4 * 4 + 1] = b.y;
      Bls[t][s4 * 4 + 2] = b.z;  Bls[t][s4 * 4 + 3] = b.w;
      Cls[t][s4 * 4 + 0] = cc.x; Cls[t][s4 * 4 + 1] = cc.y;
      Cls[t][s4 * 4 + 2] = cc.z; Cls[t][s4 * 4 + 3] = cc.w;
    }
    __syncthreads();
    const int t = threadIdx.x >> 3;
    const int tp0 = (threadIdx.x & 7) * 4;
    float g[4];
#pragma unroll
    for (int q = 0; q < 4; ++q) {
      const int tp = tp0 + q;
      float acc = 0.f;
      if (tp <= t) {
#pragma unroll
        for (int s = 0; s < 32; ++s) acc = fmaf(Cls[t][s], Bls[tp][s], acc);
      }
      g[q] = acc;
    }
    ushort4 o;
    o.x = f2bf(g[0]); o.y = f2bf(g[1]); o.z = f2bf(g[2]); o.w = f2bf(g[3]);
    reinterpret_cast<ushort4*>(Gm + c * 1024)[threadIdx.x] = o;
  }
}

// ---------------------------------------------------------------------------
// S2 state scan
// ---------------------------------------------------------------------------
__global__ __launch_bounds__(256) void state_scan_kernel(
    const float* __restrict__ V, const float* __restrict__ Pc,
    float* __restrict__ Hin) {
  const int gt = blockIdx.x * 256 + threadIdx.x;  // d*32+s
  const int d = gt >> 5;
  float h = 0.f;
  for (int c = 0; c < NCHUNK; ++c) {
    Hin[c * 16384 + gt] = h;
    h = Pc[c * D_DIM + d] * (h + V[c * 16384 + gt]);
  }
}

// ---------------------------------------------------------------------------
// S3: intra+inter output + fused gate -> comb[:, :512] (bf16, ld 1536)
// ---------------------------------------------------------------------------
__global__ __launch_bounds__(256) void ssm_out_kernel(
    const unsigned short* __restrict__ Gm, const unsigned short* __restrict__ U_T,
    const float* __restrict__ Hin, const float* __restrict__ Cm,
    const float* __restrict__ E, const float* __restrict__ xs,
    const float* __restrict__ Dp, const float* __restrict__ xz,
    unsigned short* __restrict__ comb) {
  const int c = blockIdx.x;
  const int dt0 = blockIdx.y * 64;
  __shared__ bf16x8 Als[32 * 8];
  __shared__ bf16x8 Bls[64 * 8];
  const int tid = threadIdx.x;

  if (tid < 128) {
    const int t = tid >> 2, q = tid & 3;
    Als[t * 8 + (q ^ (t & 7))] =
        *reinterpret_cast<const bf16x8*>(Gm + c * 1024 + t * 32 + q * 8);
  } else {
    const int i = tid - 128;
    const int t = i >> 2, q = i & 3;
    const float* cp = Cm + (c * CLEN + t) * 32 + q * 8;
    const float4 c0 = *reinterpret_cast<const float4*>(cp);
    const float4 c1 = *reinterpret_cast<const float4*>(cp + 4);
    union { bf16x8 v; unsigned short u[8]; } wv;
    wv.u[0] = f2bf(c0.x); wv.u[1] = f2bf(c0.y); wv.u[2] = f2bf(c0.z); wv.u[3] = f2bf(c0.w);
    wv.u[4] = f2bf(c1.x); wv.u[5] = f2bf(c1.y); wv.u[6] = f2bf(c1.z); wv.u[7] = f2bf(c1.w);
    Als[t * 8 + ((4 + q) ^ (t & 7))] = wv.v;
  }
  {
    const int dd = tid >> 2, q = tid & 3;
    Bls[dd * 8 + (q ^ (dd & 7))] = *reinterpret_cast<const bf16x8*>(
        U_T + (size_t)(dt0 + dd) * T_LEN + c * CLEN + q * 8);
    const float* hp = Hin + ((size_t)c * D_DIM + dt0 + dd) * 32 + q * 8;
    const float4 h0 = *reinterpret_cast<const float4*>(hp);
    const float4 h1 = *reinterpret_cast<const float4*>(hp + 4);
    union { bf16x8 v; unsigned short u[8]; } wv;
    wv.u[0] = f2bf(h0.x); wv.u[1] = f2bf(h0.y); wv.u[2] = f2bf(h0.z); wv.u[3] = f2bf(h0.w);
    wv.u[4] = f2bf(h1.x); wv.u[5] = f2bf(h1.y); wv.u[6] = f2bf(h1.z); wv.u[7] = f2bf(h1.w);
    Bls[dd * 8 + ((4 + q) ^ (dd & 7))] = wv.v;
  }
  __syncthreads();

  const int lane = tid & 63;
  const int w = tid >> 6;
  const int wcol = w * 16;
  f32x4 acc[2];
  acc[0] = {0.f, 0.f, 0.f, 0.f};
  acc[1] = {0.f, 0.f, 0.f, 0.f};
#pragma unroll
  for (int kk = 0; kk < 2; ++kk) {
    const int slot = kk * 4 + (lane >> 4);
    const int rb = wcol + (lane & 15);
    const bf16x8 bfrag = Bls[rb * 8 + (slot ^ (rb & 7))];
#pragma unroll
    for (int m = 0; m < 2; ++m) {
      const int r = m * 16 + (lane & 15);
      const bf16x8 afrag = Als[r * 8 + (slot ^ (r & 7))];
      acc[m] = __builtin_amdgcn_mfma_f32_16x16x32_bf16(afrag, bfrag, acc[m], 0, 0, 0);
    }
  }
  const int dg = dt0 + wcol + (lane & 15);
  const float dpv = Dp[dg];
#pragma unroll
  for (int m = 0; m < 2; ++m) {
#pragma unroll
    for (int j = 0; j < 4; ++j) {
      const int tg = c * CLEN + m * 16 + (lane >> 4) * 4 + j;
      const float y = E[(size_t)tg * D_DIM + dg] * acc[m][j];
      const float xv = xs[(size_t)tg * D_DIM + dg];
      const float zv = xz[(size_t)tg * 1024 + 512 + dg];
      comb[(size_t)tg * 1536 + dg] = f2bf(fmaf(xv, dpv, y) * silu_f(zv));
    }
  }
}

// ---------------------------------------------------------------------------
extern "C" void kernel_launch(void* const* d_in, const int* in_sizes, int n_in,
                              void* d_out, int out_size, void* d_ws, size_t ws_size,
                              hipStream_t stream) {
  const float* x      = (const float*)d_in[0];
  const float* norm_w = (const float*)d_in[1];
  const float* W_in   = (const float*)d_in[2];
  const float* conv_w = (const float*)d_in[3];
  const float* conv_b = (const float*)d_in[4];
  const float* W_dt   = (const float*)d_in[5];
  const float* b_dt   = (const float*)d_in[6];
  const float* W_B    = (const float*)d_in[7];
  const float* W_C    = (const float*)d_in[8];
  const float* W_out  = (const float*)d_in[9];
  const float* log_A  = (const float*)d_in[10];
  const float* D_par  = (const float*)d_in[11];
  const float* W_ffn1 = (const float*)d_in[12];
  const float* W_ffn2 = (const float*)d_in[13];
  const float* W_mrg  = (const float*)d_in[14];
  float* out = (float*)d_out;

  const size_t M1 = 1u << 20;
  char* ws = (char*)d_ws;
  size_t off = 0;
  auto alloc_f = [&](size_t n) { float* p = (float*)(ws + off); off += n * 4; return p; };
  auto alloc_h = [&](size_t n) { unsigned short* p = (unsigned short*)(ws + off); off += n * 2; return p; };

  float* xz  = alloc_f(2 * M1);   // [2048][1024]
  float* xs  = alloc_f(M1);
  float* dt  = alloc_f(M1);
  float* E   = alloc_f(M1);
  float* V   = alloc_f(M1);       // [64][512][32]
  float* Hin = alloc_f(M1);       // [64][512][32]
  float* Bm  = alloc_f(1 << 16);
  float* Cm  = alloc_f(1 << 16);
  float* Pc  = alloc_f(NCHUNK * D_DIM);
  unsigned short* U_T    = alloc_h(M1);            // [512][2048]
  unsigned short* Gm     = alloc_h(NCHUNK * 1024);
  unsigned short* xn_bf  = alloc_h(M1);
  unsigned short* xs_bf  = alloc_h(M1);
  unsigned short* comb   = alloc_h(2048 * 1536);   // [g | h1]
  unsigned short* WinF1T = alloc_h(2048 * 512);    // W_in cols ++ W_ffn1 cols
  unsigned short* WdtBCT = alloc_h(576 * 512);     // W_dt ++ W_B ++ W_C
  unsigned short* WmT    = alloc_h(512 * 1024);    // W_mrg^T
  unsigned short* WoutBF = alloc_h(512 * 512);     // W_out row-major bf16
  unsigned short* Wf2BF  = alloc_h(1024 * 512);    // W_ffn2 row-major bf16
  unsigned short* WcombT = alloc_h(512 * 1536);    // combined merge weights^T

  // --- fused weight prep + rmsnorm (1 launch) ---
  TransJobs J;
  J.src[0] = W_in;   J.dst[0] = WinF1T;              J.K[0] = 512;  J.N[0] = 1024; J.tr[0] = 1;
  J.src[1] = W_ffn1; J.dst[1] = WinF1T + 1024 * 512; J.K[1] = 512;  J.N[1] = 1024; J.tr[1] = 1;
  J.src[2] = W_dt;   J.dst[2] = WdtBCT;              J.K[2] = 512;  J.N[2] = 512;  J.tr[2] = 1;
  J.src[3] = W_B;    J.dst[3] = WdtBCT + 512 * 512;  J.K[3] = 512;  J.N[3] = 32;   J.tr[3] = 1;
  J.src[4] = W_C;    J.dst[4] = WdtBCT + 544 * 512;  J.K[4] = 512;  J.N[4] = 32;   J.tr[4] = 1;
  J.src[5] = W_mrg;  J.dst[5] = WmT;                 J.K[5] = 1024; J.N[5] = 512;  J.tr[5] = 1;
  J.src[6] = W_out;  J.dst[6] = WoutBF;              J.K[6] = 512;  J.N[6] = 512;  J.tr[6] = 0;
  J.src[7] = W_ffn2; J.dst[7] = Wf2BF;               J.K[7] = 1024; J.N[7] = 512;  J.tr[7] = 0;
  int bacc = 0;
  for (int i = 0; i < 8; ++i) {
    J.b0[i] = bacc;
    bacc += (J.N[i] >> 5) * (J.K[i] >> 5);
  }
  J.b0[8] = bacc;  // 2592
  prep_rms_kernel<<<bacc + T_LEN, 256, 0, stream>>>(J, x, norm_w, xn_bf);

  // 2. fused: input projection (1024 blks) + weight combine (192 blks)
  gemm_in_combine<<<1216, 256, 0, stream>>>(
      xn_bf, WinF1T, xz, comb, WmT, WoutBF, Wf2BF, WcombT);
  // 3. conv + silu
  conv_silu_kernel<<<4096, 256, 0, stream>>>(xz, conv_w, conv_b, xs, xs_bf);
  // 4. fused: [dt | Bm | Cm] = xs @ [W_dt | W_B | W_C]  (N=576)
  gemm64_dtbc<<<dim3(9, 32), 256, 0, stream>>>(xs_bf, WdtBCT, dt, Bm, Cm, b_dt);
  // 5. fused chunk prep + gram
  prep_gram_kernel<<<192, 256, 0, stream>>>(dt, xs, Bm, Cm, log_A, U_T, E, V, Pc, Gm);
  // 6. inter-chunk state scan
  state_scan_kernel<<<64, 256, 0, stream>>>(V, Pc, Hin);
  // 7. SSM output + fused gate -> comb[:, :512]
  ssm_out_kernel<<<dim3(NCHUNK, 8), 256, 0, stream>>>(Gm, U_T, Hin, Cm, E, xs, D_par, xz, comb);
  // 8. out = x + comb @ Wcomb  (split-K within block, 512 threads)
  gemm64_merge_kp<<<dim3(8, 32), 512, 0, stream>>>(comb, WcombT, out, x);
}

// Round 14
// 86.233 us; speedup vs baseline: 1.6413x; 1.0074x over previous
//
#include <hip/hip_runtime.h>
#include <math.h>

// Problem constants: B=1, T=2048, D=512, DS=32, EXP=2
#define T_LEN 2048
#define D_DIM 512
#define NCHUNK 64
#define CLEN 32

typedef __bf16 bf16x8 __attribute__((ext_vector_type(8)));
typedef float f32x4 __attribute__((ext_vector_type(4)));

typedef const __attribute__((address_space(1))) void gvoid;
typedef __attribute__((address_space(3))) void lvoid;

// async global->LDS, 16B per lane; lds dest is wave-uniform base + lane*16
__device__ __forceinline__ void async16(const void* g, void* l) {
  __builtin_amdgcn_global_load_lds((gvoid*)g, (lvoid*)l, 16, 0, 0);
}

__device__ __forceinline__ float silu_f(float x) { return x / (1.f + __expf(-x)); }
__device__ __forceinline__ float softplus_f(float x) {
  return fmaxf(x, 0.f) + log1pf(__expf(-fabsf(x)));
}
__device__ __forceinline__ float gelu_f(float x) {
  return 0.5f * x * (1.f + erff(x * 0.70710678118654752440f));
}
__device__ __forceinline__ unsigned short f2bf(float f) {
  union { float f; unsigned u; } v; v.f = f;
  unsigned r = v.u + 0x7FFF + ((v.u >> 16) & 1);  // round-nearest-even
  return (unsigned short)(r >> 16);
}

// ---------------------------------------------------------------------------
// Fused weight prep (8 transpose/convert jobs) + RMSNorm.
// ---------------------------------------------------------------------------
struct TransJobs {
  const float* src[8];
  unsigned short* dst[8];
  int K[8];
  int N[8];
  int tr[8];
  int b0[9];
};

__global__ __launch_bounds__(256) void prep_rms_kernel(
    TransJobs J, const float* __restrict__ x, const float* __restrict__ nw,
    unsigned short* __restrict__ xn) {
  const int b = blockIdx.x;
  if (b >= J.b0[8]) {
    // ---- RMSNorm row t ----
    const int t = b - J.b0[8];
    const float2 v = reinterpret_cast<const float2*>(x + (size_t)t * D_DIM)[threadIdx.x];
    float ss = v.x * v.x + v.y * v.y;
#pragma unroll
    for (int m = 1; m < 64; m <<= 1) ss += __shfl_xor(ss, m);
    __shared__ float wsum[4];
    if ((threadIdx.x & 63) == 0) wsum[threadIdx.x >> 6] = ss;
    __syncthreads();
    const float tot = wsum[0] + wsum[1] + wsum[2] + wsum[3];
    const float scale = rsqrtf(tot * (1.f / D_DIM) + 1e-6f);
    const float2 wv = reinterpret_cast<const float2*>(nw)[threadIdx.x];
    ushort2 o;
    o.x = f2bf(v.x * scale * wv.x);
    o.y = f2bf(v.y * scale * wv.y);
    reinterpret_cast<ushort2*>(xn + (size_t)t * D_DIM)[threadIdx.x] = o;
    return;
  }
  __shared__ float tile[32][33];
  int ji = 0;
#pragma unroll
  for (int i = 1; i < 8; ++i) ji += (b >= J.b0[i]) ? 1 : 0;
  const float* __restrict__ src = J.src[ji];
  unsigned short* __restrict__ dst = J.dst[ji];
  const int K = J.K[ji], N = J.N[ji];
  const int rel = b - J.b0[ji];
  const int nbx = N >> 5;
  const int bx = rel % nbx, by = rel / nbx;
  const int k0 = by * 32, n0 = bx * 32;
  const int i = threadIdx.x & 31;
  const int r = threadIdx.x >> 5;
  if (J.tr[ji]) {
#pragma unroll
    for (int p = 0; p < 4; ++p) {
      const int kk = r + p * 8;
      tile[kk][i] = src[(size_t)(k0 + kk) * N + n0 + i];
    }
    __syncthreads();
#pragma unroll
    for (int p = 0; p < 4; ++p) {
      const int nn = r + p * 8;
      dst[(size_t)(n0 + nn) * K + k0 + i] = f2bf(tile[i][nn]);
    }
  } else {
#pragma unroll
    for (int p = 0; p < 4; ++p) {
      const int kk = r + p * 8;
      dst[(size_t)(k0 + kk) * N + n0 + i] = f2bf(src[(size_t)(k0 + kk) * N + n0 + i]);
    }
  }
}

// ---------------------------------------------------------------------------
// 64x64 MFMA core (parameterized tid), BK=64, double-buffered async staging.
// LDS linear dest + inverse-swizzled global src + swizzled read (involution).
// ---------------------------------------------------------------------------
__device__ __forceinline__ void gemm64_core_t(
    int tid,
    const unsigned short* __restrict__ Abf, const unsigned short* __restrict__ Btbf,
    int nt, int lda8, int ldb8, int brow, int bcol,
    bf16x8* __restrict__ As, bf16x8* __restrict__ Bs, f32x4 acc[2][2]) {
  const int lane = tid & 63;
  const int w = tid >> 6;
  const int wrow = (w >> 1) * 32;
  const int wcol = (w & 1) * 32;
  const bf16x8* __restrict__ A8 = reinterpret_cast<const bf16x8*>(Abf);
  const bf16x8* __restrict__ B8 = reinterpret_cast<const bf16x8*>(Btbf);

  const int lr = lane >> 3;
  const int ls = (lane & 7) ^ lr;
  const int wb = w * 64;
  const size_t a0 = (size_t)(brow + w * 8 + lr) * lda8 + ls;
  const size_t a1 = (size_t)(brow + 32 + w * 8 + lr) * lda8 + ls;
  const size_t b0 = (size_t)(bcol + w * 8 + lr) * ldb8 + ls;
  const size_t b1 = (size_t)(bcol + 32 + w * 8 + lr) * ldb8 + ls;

  async16(A8 + a0, As + wb);
  async16(A8 + a1, As + 256 + wb);
  async16(B8 + b0, Bs + wb);
  async16(B8 + b1, Bs + 256 + wb);
  __syncthreads();

  int cur = 0;
  for (int t = 0; t < nt; ++t) {
    if (t + 1 < nt) {
      const int kb = (t + 1) * 8;
      const int nx = (cur ^ 1) * 512;
      async16(A8 + a0 + kb, As + nx + wb);
      async16(A8 + a1 + kb, As + nx + 256 + wb);
      async16(B8 + b0 + kb, Bs + nx + wb);
      async16(B8 + b1 + kb, Bs + nx + 256 + wb);
    }
    const bf16x8* __restrict__ Ac = As + cur * 512;
    const bf16x8* __restrict__ Bc = Bs + cur * 512;
#pragma unroll
    for (int kk = 0; kk < 2; ++kk) {
      const int slot = kk * 4 + (lane >> 4);
      bf16x8 af[2], bf_[2];
#pragma unroll
      for (int m = 0; m < 2; ++m) {
        const int r = wrow + m * 16 + (lane & 15);
        af[m] = Ac[r * 8 + (slot ^ (r & 7))];
      }
#pragma unroll
      for (int n = 0; n < 2; ++n) {
        const int r = wcol + n * 16 + (lane & 15);
        bf_[n] = Bc[r * 8 + (slot ^ (r & 7))];
      }
#pragma unroll
      for (int m = 0; m < 2; ++m)
#pragma unroll
        for (int n = 0; n < 2; ++n)
          acc[m][n] = __builtin_amdgcn_mfma_f32_16x16x32_bf16(af[m], bf_[n], acc[m][n], 0, 0, 0);
    }
    __syncthreads();
    cur ^= 1;
  }
}

__device__ __forceinline__ void gemm64_core(
    const unsigned short* __restrict__ Abf, const unsigned short* __restrict__ Btbf,
    int nt, int lda8, int ldb8, int brow, int bcol,
    bf16x8* __restrict__ As, bf16x8* __restrict__ Bs, f32x4 acc[2][2]) {
  gemm64_core_t(threadIdx.x, Abf, Btbf, nt, lda8, ldb8, brow, bcol, As, Bs, acc);
}

// ---------------------------------------------------------------------------
// Fused launch: blocks 0..1023   : [xz | h1] = xn @ [W_in | W_ffn1] (N=2048)
//               blocks 1024..1087: WcombT[:, :512]  = WmT[:, :512] @ W_out^T
//               blocks 1088..1215: WcombT[:, 512:]  = WmT[:, 512:] @ W_ffn2^T
// ---------------------------------------------------------------------------
__global__ __launch_bounds__(256) void gemm_in_combine(
    const unsigned short* __restrict__ xn_bf, const unsigned short* __restrict__ WinF1T,
    float* __restrict__ xz, unsigned short* __restrict__ comb,
    const unsigned short* __restrict__ WmT, const unsigned short* __restrict__ WoutBF,
    const unsigned short* __restrict__ Wf2BF, unsigned short* __restrict__ WcombT) {
  __shared__ bf16x8 As[1024];
  __shared__ bf16x8 Bs[1024];
  f32x4 acc[2][2];
#pragma unroll
  for (int m = 0; m < 2; ++m)
#pragma unroll
    for (int n = 0; n < 2; ++n) acc[m][n] = {0.f, 0.f, 0.f, 0.f};

  const int b = blockIdx.x;
  const int lane = threadIdx.x & 63;
  const int w = threadIdx.x >> 6;
  const int wrow = (w >> 1) * 32;
  const int wcol = (w & 1) * 32;

  if (b < 1024) {
    const int brow = (b >> 5) * 64;
    const int bcol = (b & 31) * 64;
    gemm64_core(xn_bf, WinF1T, 8, 64, 64, brow, bcol, As, Bs, acc);
#pragma unroll
    for (int m = 0; m < 2; ++m) {
#pragma unroll
      for (int n = 0; n < 2; ++n) {
        const int col = bcol + wcol + n * 16 + (lane & 15);
#pragma unroll
        for (int j = 0; j < 4; ++j) {
          const int row = brow + wrow + m * 16 + (lane >> 4) * 4 + j;
          const float v = acc[m][n][j];
          if (col < 1024) {
            xz[(size_t)row * 1024 + col] = v;
          } else {
            comb[(size_t)row * 1536 + 512 + (col - 1024)] = f2bf(gelu_f(v));
          }
        }
      }
    }
  } else if (b < 1088) {
    const int rel = b - 1024;
    const int brow = (rel >> 3) * 64;
    const int bcol = (rel & 7) * 64;
    gemm64_core(WmT, WoutBF, 8, 128, 64, brow, bcol, As, Bs, acc);
#pragma unroll
    for (int m = 0; m < 2; ++m) {
#pragma unroll
      for (int n = 0; n < 2; ++n) {
        const int col = bcol + wcol + n * 16 + (lane & 15);
#pragma unroll
        for (int j = 0; j < 4; ++j) {
          const int row = brow + wrow + m * 16 + (lane >> 4) * 4 + j;
          WcombT[(size_t)row * 1536 + col] = f2bf(acc[m][n][j]);
        }
      }
    }
  } else {
    const int rel = b - 1088;
    const int brow = (rel >> 4) * 64;
    const int bcol = (rel & 15) * 64;
    gemm64_core(WmT + 512, Wf2BF, 8, 128, 64, brow, bcol, As, Bs, acc);
#pragma unroll
    for (int m = 0; m < 2; ++m) {
#pragma unroll
      for (int n = 0; n < 2; ++n) {
        const int col = bcol + wcol + n * 16 + (lane & 15);
#pragma unroll
        for (int j = 0; j < 4; ++j) {
          const int row = brow + wrow + m * 16 + (lane >> 4) * 4 + j;
          WcombT[(size_t)row * 1536 + 512 + col] = f2bf(acc[m][n][j]);
        }
      }
    }
  }
}

// ---------------------------------------------------------------------------
// dt/B/C GEMM, split-K WITHIN block: 512 threads = 2 groups x 4 waves.
// Group g covers K [g*256,(g+1)*256) (nt=4). Group 1 -> LDS; group 0 reduces
// and applies softplus/bias epilogue. Grid (9,32); 64KB LDS.
// ---------------------------------------------------------------------------
__global__ __launch_bounds__(512) void gemm64_dtbc_kp(
    const unsigned short* __restrict__ Abf, const unsigned short* __restrict__ Btbf,
    float* __restrict__ dt, float* __restrict__ Bm, float* __restrict__ Cm,
    const float* __restrict__ bias) {
  __shared__ bf16x8 As[2][1024];
  __shared__ bf16x8 Bs[2][1024];
  const int tid = threadIdx.x;
  const int g = tid >> 8;       // K-group
  const int t256 = tid & 255;
  f32x4 acc[2][2];
#pragma unroll
  for (int m = 0; m < 2; ++m)
#pragma unroll
    for (int n = 0; n < 2; ++n) acc[m][n] = {0.f, 0.f, 0.f, 0.f};
  const int brow = blockIdx.y * 64;
  const int bcol = blockIdx.x * 64;
  // K offset: g*256 bf16 = g*32 bf16x8 units
  gemm64_core_t(t256, Abf + (size_t)g * 256, Btbf + (size_t)g * 256,
                4, 64, 64, brow, bcol, As[g], Bs[g], acc);

  const int lane = t256 & 63;
  const int w = t256 >> 6;
  const int wrow = (w >> 1) * 32;
  const int wcol = (w & 1) * 32;
  float* red = reinterpret_cast<float*>(&As[0][0]);  // 64x64 f32 = 16KB
  __syncthreads();
  if (g == 1) {
#pragma unroll
    for (int m = 0; m < 2; ++m)
#pragma unroll
      for (int n = 0; n < 2; ++n)
#pragma unroll
        for (int j = 0; j < 4; ++j) {
          const int r = wrow + m * 16 + (lane >> 4) * 4 + j;
          const int c = wcol + n * 16 + (lane & 15);
          red[r * 64 + c] = acc[m][n][j];
        }
  }
  __syncthreads();
  if (g == 0) {
#pragma unroll
    for (int m = 0; m < 2; ++m) {
#pragma unroll
      for (int n = 0; n < 2; ++n) {
        const int c = wcol + n * 16 + (lane & 15);
        const int col = bcol + c;
#pragma unroll
        for (int j = 0; j < 4; ++j) {
          const int r = wrow + m * 16 + (lane >> 4) * 4 + j;
          const int row = brow + r;
          const float v = acc[m][n][j] + red[r * 64 + c];
          if (col < 512) {
            dt[(size_t)row * 512 + col] = softplus_f(v + bias[col]);
          } else {
            const int s = col - 512;
            float* p = (s < 32) ? Bm : Cm;
            p[(size_t)row * 32 + (s & 31)] = v;
          }
        }
      }
    }
  }
}

// ---------------------------------------------------------------------------
// Final GEMM, split-K WITHIN block: 512 threads = 2 groups x 4 waves.
// ---------------------------------------------------------------------------
__global__ __launch_bounds__(512) void gemm64_merge_kp(
    const unsigned short* __restrict__ Abf, const unsigned short* __restrict__ Btbf,
    float* __restrict__ out, const float* __restrict__ resid) {
  __shared__ bf16x8 As[2][1024];
  __shared__ bf16x8 Bs[2][1024];
  const int tid = threadIdx.x;
  const int g = tid >> 8;       // K-group
  const int t256 = tid & 255;
  f32x4 acc[2][2];
#pragma unroll
  for (int m = 0; m < 2; ++m)
#pragma unroll
    for (int n = 0; n < 2; ++n) acc[m][n] = {0.f, 0.f, 0.f, 0.f};
  const int brow = blockIdx.y * 64;
  const int bcol = blockIdx.x * 64;
  // K offset: g*768 bf16 = g*96 bf16x8 units
  gemm64_core_t(t256, Abf + (size_t)g * 768, Btbf + (size_t)g * 768,
                12, 192, 192, brow, bcol, As[g], Bs[g], acc);

  const int lane = t256 & 63;
  const int w = t256 >> 6;
  const int wrow = (w >> 1) * 32;
  const int wcol = (w & 1) * 32;
  float* red = reinterpret_cast<float*>(&As[0][0]);  // 64x64 f32 = 16KB
  __syncthreads();
  if (g == 1) {
#pragma unroll
    for (int m = 0; m < 2; ++m)
#pragma unroll
      for (int n = 0; n < 2; ++n)
#pragma unroll
        for (int j = 0; j < 4; ++j) {
          const int r = wrow + m * 16 + (lane >> 4) * 4 + j;
          const int c = wcol + n * 16 + (lane & 15);
          red[r * 64 + c] = acc[m][n][j];
        }
  }
  __syncthreads();
  if (g == 0) {
#pragma unroll
    for (int m = 0; m < 2; ++m) {
#pragma unroll
      for (int n = 0; n < 2; ++n) {
        const int c = wcol + n * 16 + (lane & 15);
        const int col = bcol + c;
#pragma unroll
        for (int j = 0; j < 4; ++j) {
          const int r = wrow + m * 16 + (lane >> 4) * 4 + j;
          const int row = brow + r;
          out[(size_t)row * 512 + col] =
              resid[(size_t)row * 512 + col] + acc[m][n][j] + red[r * 64 + c];
        }
      }
    }
  }
}

// ---------------------------------------------------------------------------
// Causal depthwise conv (k=4) + bias + SiLU -> f32 + bf16
// ---------------------------------------------------------------------------
__global__ __launch_bounds__(256) void conv_silu_kernel(
    const float* __restrict__ xz, const float* __restrict__ cw,
    const float* __restrict__ cb, float* __restrict__ xs,
    unsigned short* __restrict__ xs_bf) {
  const int idx = blockIdx.x * 256 + threadIdx.x;
  const int t = idx >> 9;
  const int d = idx & 511;
  const float4 w = reinterpret_cast<const float4*>(cw)[d];
  float acc = cb[d];
  const float wk[4] = {w.x, w.y, w.z, w.w};
#pragma unroll
  for (int k = 0; k < 4; ++k) {
    const int tt = t - 3 + k;
    if (tt >= 0) acc = fmaf(xz[(size_t)tt * 1024 + d], wk[k], acc);
  }
  const float s = silu_f(acc);
  xs[idx] = s;
  xs_bf[idx] = f2bf(s);
}

// ---------------------------------------------------------------------------
// Fused S1 chunk prep (blocks 0..127) + Gram (blocks 128..191), one launch.
// ---------------------------------------------------------------------------
__global__ __launch_bounds__(256) void prep_gram_kernel(
    const float* __restrict__ dt, const float* __restrict__ xs,
    const float* __restrict__ Bm, const float* __restrict__ Cm,
    const float* __restrict__ log_A,
    unsigned short* __restrict__ U_T, float* __restrict__ E,
    float* __restrict__ V, float* __restrict__ Pc,
    unsigned short* __restrict__ Gm) {
  __shared__ float4 Bls4[CLEN * 8];
  __shared__ float Bls[32][33], Cls[32][33];

  if (blockIdx.x < 128) {
    const int c = blockIdx.x >> 1;
    const int d = (blockIdx.x & 1) * 256 + threadIdx.x;
    Bls4[threadIdx.x] = reinterpret_cast<const float4*>(Bm + c * CLEN * 32)[threadIdx.x];
    __syncthreads();

    const float A = -__expf(log_A[d]);
    float cum = 0.f;
    float e = 1.f;
    float vacc[32];
#pragma unroll
    for (int s = 0; s < 32; ++s) vacc[s] = 0.f;
    unsigned pk[16];
#pragma unroll
    for (int t = 0; t < CLEN; ++t) {
      const int tg = c * CLEN + t;
      const float dtv = dt[(size_t)tg * D_DIM + d];
      const float xv  = xs[(size_t)tg * D_DIM + d];
      const float la = fminf(fmaxf(dtv * A, -20.f), 20.f);
      cum += la;
      e = __expf(cum);
      E[(size_t)tg * D_DIM + d] = e;
      const float u = __expf(-cum) * dtv * xv;
      const unsigned short ub = f2bf(u);
      if ((t & 1) == 0) pk[t >> 1] = (unsigned)ub;
      else              pk[t >> 1] |= ((unsigned)ub) << 16;
#pragma unroll
      for (int s4 = 0; s4 < 8; ++s4) {
        const float4 b = Bls4[t * 8 + s4];
        vacc[s4 * 4 + 0] = fmaf(u, b.x, vacc[s4 * 4 + 0]);
        vacc[s4 * 4 + 1] = fmaf(u, b.y, vacc[s4 * 4 + 1]);
        vacc[s4 * 4 + 2] = fmaf(u, b.z, vacc[s4 * 4 + 2]);
        vacc[s4 * 4 + 3] = fmaf(u, b.w, vacc[s4 * 4 + 3]);
      }
    }
    {
      uint4* dst = reinterpret_cast<uint4*>(U_T + (size_t)d * T_LEN + c * CLEN);
      dst[0] = make_uint4(pk[0], pk[1], pk[2], pk[3]);
      dst[1] = make_uint4(pk[4], pk[5], pk[6], pk[7]);
      dst[2] = make_uint4(pk[8], pk[9], pk[10], pk[11]);
      dst[3] = make_uint4(pk[12], pk[13], pk[14], pk[15]);
    }
    {
      float4* dst = reinterpret_cast<float4*>(V + ((size_t)c * D_DIM + d) * 32);
#pragma unroll
      for (int s4 = 0; s4 < 8; ++s4)
        dst[s4] = make_float4(vacc[s4 * 4], vacc[s4 * 4 + 1], vacc[s4 * 4 + 2], vacc[s4 * 4 + 3]);
    }
    Pc[c * D_DIM + d] = e;
  } else {
    const int c = blockIdx.x - 128;
    {
      const int t = threadIdx.x >> 3;
      const int s4 = threadIdx.x & 7;
      const float4 b = reinterpret_cast<const float4*>(Bm + (c * CLEN + t) * 32)[s4];
      const float4 cc = reinterpret_cast<const float4*>(Cm + (c * CLEN + t) * 32)[s4];
      Bls[t][s4 * 4 + 0] = b.x;  Bls[t][s4 * 4 + 1] = b.y;
      Bls[t][s4 * 4 + 2] = b.z;  Bls[t][s4 * 4 + 3] = b.w;
      Cls[t][s4 * 4 + 0] = cc.x; Cls[t][s4 * 4 + 1] = cc.y;
      Cls[t][s4 * 4 + 2] = cc.z; Cls[t][s4 * 4 + 3] = cc.w;
    }
    __syncthreads();
    const int t = threadIdx.x >> 3;
    const int tp0 = (threadIdx.x & 7) * 4;
    float g[4];
#pragma unroll
    for (int q = 0; q < 4; ++q) {
      const int tp = tp0 + q;
      float acc = 0.f;
      if (tp <= t) {
#pragma unroll
        for (int s = 0; s < 32; ++s) acc = fmaf(Cls[t][s], Bls[tp][s], acc);
      }
      g[q] = acc;
    }
    ushort4 o;
    o.x = f2bf(g[0]); o.y = f2bf(g[1]); o.z = f2bf(g[2]); o.w = f2bf(g[3]);
    reinterpret_cast<ushort4*>(Gm + c * 1024)[threadIdx.x] = o;
  }
}

// ---------------------------------------------------------------------------
// S2 state scan
// ---------------------------------------------------------------------------
__global__ __launch_bounds__(256) void state_scan_kernel(
    const float* __restrict__ V, const float* __restrict__ Pc,
    float* __restrict__ Hin) {
  const int gt = blockIdx.x * 256 + threadIdx.x;  // d*32+s
  const int d = gt >> 5;
  float h = 0.f;
  for (int c = 0; c < NCHUNK; ++c) {
    Hin[c * 16384 + gt] = h;
    h = Pc[c * D_DIM + d] * (h + V[c * 16384 + gt]);
  }
}

// ---------------------------------------------------------------------------
// S3: intra+inter output + fused gate -> comb[:, :512] (bf16, ld 1536)
// ---------------------------------------------------------------------------
__global__ __launch_bounds__(256) void ssm_out_kernel(
    const unsigned short* __restrict__ Gm, const unsigned short* __restrict__ U_T,
    const float* __restrict__ Hin, const float* __restrict__ Cm,
    const float* __restrict__ E, const float* __restrict__ xs,
    const float* __restrict__ Dp, const float* __restrict__ xz,
    unsigned short* __restrict__ comb) {
  const int c = blockIdx.x;
  const int dt0 = blockIdx.y * 64;
  __shared__ bf16x8 Als[32 * 8];
  __shared__ bf16x8 Bls[64 * 8];
  const int tid = threadIdx.x;

  if (tid < 128) {
    const int t = tid >> 2, q = tid & 3;
    Als[t * 8 + (q ^ (t & 7))] =
        *reinterpret_cast<const bf16x8*>(Gm + c * 1024 + t * 32 + q * 8);
  } else {
    const int i = tid - 128;
    const int t = i >> 2, q = i & 3;
    const float* cp = Cm + (c * CLEN + t) * 32 + q * 8;
    const float4 c0 = *reinterpret_cast<const float4*>(cp);
    const float4 c1 = *reinterpret_cast<const float4*>(cp + 4);
    union { bf16x8 v; unsigned short u[8]; } wv;
    wv.u[0] = f2bf(c0.x); wv.u[1] = f2bf(c0.y); wv.u[2] = f2bf(c0.z); wv.u[3] = f2bf(c0.w);
    wv.u[4] = f2bf(c1.x); wv.u[5] = f2bf(c1.y); wv.u[6] = f2bf(c1.z); wv.u[7] = f2bf(c1.w);
    Als[t * 8 + ((4 + q) ^ (t & 7))] = wv.v;
  }
  {
    const int dd = tid >> 2, q = tid & 3;
    Bls[dd * 8 + (q ^ (dd & 7))] = *reinterpret_cast<const bf16x8*>(
        U_T + (size_t)(dt0 + dd) * T_LEN + c * CLEN + q * 8);
    const float* hp = Hin + ((size_t)c * D_DIM + dt0 + dd) * 32 + q * 8;
    const float4 h0 = *reinterpret_cast<const float4*>(hp);
    const float4 h1 = *reinterpret_cast<const float4*>(hp + 4);
    union { bf16x8 v; unsigned short u[8]; } wv;
    wv.u[0] = f2bf(h0.x); wv.u[1] = f2bf(h0.y); wv.u[2] = f2bf(h0.z); wv.u[3] = f2bf(h0.w);
    wv.u[4] = f2bf(h1.x); wv.u[5] = f2bf(h1.y); wv.u[6] = f2bf(h1.z); wv.u[7] = f2bf(h1.w);
    Bls[dd * 8 + ((4 + q) ^ (dd & 7))] = wv.v;
  }
  __syncthreads();

  const int lane = tid & 63;
  const int w = tid >> 6;
  const int wcol = w * 16;
  f32x4 acc[2];
  acc[0] = {0.f, 0.f, 0.f, 0.f};
  acc[1] = {0.f, 0.f, 0.f, 0.f};
#pragma unroll
  for (int kk = 0; kk < 2; ++kk) {
    const int slot = kk * 4 + (lane >> 4);
    const int rb = wcol + (lane & 15);
    const bf16x8 bfrag = Bls[rb * 8 + (slot ^ (rb & 7))];
#pragma unroll
    for (int m = 0; m < 2; ++m) {
      const int r = m * 16 + (lane & 15);
      const bf16x8 afrag = Als[r * 8 + (slot ^ (r & 7))];
      acc[m] = __builtin_amdgcn_mfma_f32_16x16x32_bf16(afrag, bfrag, acc[m], 0, 0, 0);
    }
  }
  const int dg = dt0 + wcol + (lane & 15);
  const float dpv = Dp[dg];
#pragma unroll
  for (int m = 0; m < 2; ++m) {
#pragma unroll
    for (int j = 0; j < 4; ++j) {
      const int tg = c * CLEN + m * 16 + (lane >> 4) * 4 + j;
      const float y = E[(size_t)tg * D_DIM + dg] * acc[m][j];
      const float xv = xs[(size_t)tg * D_DIM + dg];
      const float zv = xz[(size_t)tg * 1024 + 512 + dg];
      comb[(size_t)tg * 1536 + dg] = f2bf(fmaf(xv, dpv, y) * silu_f(zv));
    }
  }
}

// ---------------------------------------------------------------------------
extern "C" void kernel_launch(void* const* d_in, const int* in_sizes, int n_in,
                              void* d_out, int out_size, void* d_ws, size_t ws_size,
                              hipStream_t stream) {
  const float* x      = (const float*)d_in[0];
  const float* norm_w = (const float*)d_in[1];
  const float* W_in   = (const float*)d_in[2];
  const float* conv_w = (const float*)d_in[3];
  const float* conv_b = (const float*)d_in[4];
  const float* W_dt   = (const float*)d_in[5];
  const float* b_dt   = (const float*)d_in[6];
  const float* W_B    = (const float*)d_in[7];
  const float* W_C    = (const float*)d_in[8];
  const float* W_out  = (const float*)d_in[9];
  const float* log_A  = (const float*)d_in[10];
  const float* D_par  = (const float*)d_in[11];
  const float* W_ffn1 = (const float*)d_in[12];
  const float* W_ffn2 = (const float*)d_in[13];
  const float* W_mrg  = (const float*)d_in[14];
  float* out = (float*)d_out;

  const size_t M1 = 1u << 20;
  char* ws = (char*)d_ws;
  size_t off = 0;
  auto alloc_f = [&](size_t n) { float* p = (float*)(ws + off); off += n * 4; return p; };
  auto alloc_h = [&](size_t n) { unsigned short* p = (unsigned short*)(ws + off); off += n * 2; return p; };

  float* xz  = alloc_f(2 * M1);   // [2048][1024]
  float* xs  = alloc_f(M1);
  float* dt  = alloc_f(M1);
  float* E   = alloc_f(M1);
  float* V   = alloc_f(M1);       // [64][512][32]
  float* Hin = alloc_f(M1);       // [64][512][32]
  float* Bm  = alloc_f(1 << 16);
  float* Cm  = alloc_f(1 << 16);
  float* Pc  = alloc_f(NCHUNK * D_DIM);
  unsigned short* U_T    = alloc_h(M1);            // [512][2048]
  unsigned short* Gm     = alloc_h(NCHUNK * 1024);
  unsigned short* xn_bf  = alloc_h(M1);
  unsigned short* xs_bf  = alloc_h(M1);
  unsigned short* comb   = alloc_h(2048 * 1536);   // [g | h1]
  unsigned short* WinF1T = alloc_h(2048 * 512);    // W_in cols ++ W_ffn1 cols
  unsigned short* WdtBCT = alloc_h(576 * 512);     // W_dt ++ W_B ++ W_C
  unsigned short* WmT    = alloc_h(512 * 1024);    // W_mrg^T
  unsigned short* WoutBF = alloc_h(512 * 512);     // W_out row-major bf16
  unsigned short* Wf2BF  = alloc_h(1024 * 512);    // W_ffn2 row-major bf16
  unsigned short* WcombT = alloc_h(512 * 1536);    // combined merge weights^T

  // --- fused weight prep + rmsnorm (1 launch) ---
  TransJobs J;
  J.src[0] = W_in;   J.dst[0] = WinF1T;              J.K[0] = 512;  J.N[0] = 1024; J.tr[0] = 1;
  J.src[1] = W_ffn1; J.dst[1] = WinF1T + 1024 * 512; J.K[1] = 512;  J.N[1] = 1024; J.tr[1] = 1;
  J.src[2] = W_dt;   J.dst[2] = WdtBCT;              J.K[2] = 512;  J.N[2] = 512;  J.tr[2] = 1;
  J.src[3] = W_B;    J.dst[3] = WdtBCT + 512 * 512;  J.K[3] = 512;  J.N[3] = 32;   J.tr[3] = 1;
  J.src[4] = W_C;    J.dst[4] = WdtBCT + 544 * 512;  J.K[4] = 512;  J.N[4] = 32;   J.tr[4] = 1;
  J.src[5] = W_mrg;  J.dst[5] = WmT;                 J.K[5] = 1024; J.N[5] = 512;  J.tr[5] = 1;
  J.src[6] = W_out;  J.dst[6] = WoutBF;              J.K[6] = 512;  J.N[6] = 512;  J.tr[6] = 0;
  J.src[7] = W_ffn2; J.dst[7] = Wf2BF;               J.K[7] = 1024; J.N[7] = 512;  J.tr[7] = 0;
  int bacc = 0;
  for (int i = 0; i < 8; ++i) {
    J.b0[i] = bacc;
    bacc += (J.N[i] >> 5) * (J.K[i] >> 5);
  }
  J.b0[8] = bacc;  // 2592
  prep_rms_kernel<<<bacc + T_LEN, 256, 0, stream>>>(J, x, norm_w, xn_bf);

  // 2. fused: input projection (1024 blks) + weight combine (192 blks)
  gemm_in_combine<<<1216, 256, 0, stream>>>(
      xn_bf, WinF1T, xz, comb, WmT, WoutBF, Wf2BF, WcombT);
  // 3. conv + silu
  conv_silu_kernel<<<4096, 256, 0, stream>>>(xz, conv_w, conv_b, xs, xs_bf);
  // 4. fused: [dt | Bm | Cm] = xs @ [W_dt | W_B | W_C]  (split-K, 512 thr)
  gemm64_dtbc_kp<<<dim3(9, 32), 512, 0, stream>>>(xs_bf, WdtBCT, dt, Bm, Cm, b_dt);
  // 5. fused chunk prep + gram
  prep_gram_kernel<<<192, 256, 0, stream>>>(dt, xs, Bm, Cm, log_A, U_T, E, V, Pc, Gm);
  // 6. inter-chunk state scan
  state_scan_kernel<<<64, 256, 0, stream>>>(V, Pc, Hin);
  // 7. SSM output + fused gate -> comb[:, :512]
  ssm_out_kernel<<<dim3(NCHUNK, 8), 256, 0, stream>>>(Gm, U_T, Hin, Cm, E, xs, D_par, xz, comb);
  // 8. out = x + comb @ Wcomb  (split-K within block, 512 threads)
  gemm64_merge_kp<<<dim3(8, 32), 512, 0, stream>>>(comb, WcombT, out, x);
}